// Round 9
// baseline (662.244 us; speedup 1.0000x reference)
//
#include <hip/hip_runtime.h>

// Refine: out = relu((1-a)*(W f) + a*chat[idx] + bias)
// a = exp(-(csq - 2*<f,cent[idx]> + fsq)/256), chat = W*cent
// idx = argmax_n <f, cnorm_n>
//
// ws layout (ws_size = 1 GiB; we use ~140 MB):
//  featbf [16][16384][256] bf16 @ 0          (PIXEL-major; written by k1, read by k3b)
//  cnT    [256][80] f32        @ 134217728
//  wt     [256][256] f32       @ 134299648
//  wks    [8][256][32] bf16    @ 134561792
//  centf  [16][80][256] bf16   @ 134692864
//  idxb   [16*16384] u8        @ 135348224
//  fsq    [16*16384] f32       @ 135610368
//  cnt    [16*80] i32          @ 136658944  (zeroed by k0_cnorm)
//  csq    [16*80] f32          @ 136664064
//  chat   [16][80][256] f32    @ 136669184
//  sumxp  [4][16][80][256] bf16 @ 137979904

typedef __bf16 bf16x8 __attribute__((ext_vector_type(8)));
typedef float  f32x4  __attribute__((ext_vector_type(4)));
typedef unsigned char u8;

__device__ __forceinline__ unsigned short f2b(float f) {
  unsigned u = __float_as_uint(f);
  return (unsigned short)((u + 0x7fffu + ((u >> 16) & 1u)) >> 16);
}
__device__ __forceinline__ float b2f(unsigned short s) {
  return __uint_as_float((unsigned)s << 16);
}

// ---------------- K0a: normalized centroids [c][n] + zero cntg ----------------
__global__ __launch_bounds__(256) void k0_cnorm(const float* __restrict__ cent,
                                                float* __restrict__ cnT,
                                                int* __restrict__ cntg) {
  int n = blockIdx.x, t = threadIdx.x;
  if (t < 16) cntg[n * 16 + t] = 0;
  float v = cent[n * 256 + t];
  float s = v * v;
  #pragma unroll
  for (int o = 32; o > 0; o >>= 1) s += __shfl_down(s, o, 64);
  __shared__ float red[4];
  if ((t & 63) == 0) red[t >> 6] = s;
  __syncthreads();
  float tot = red[0] + red[1] + red[2] + red[3];
  float dn = fmaxf(sqrtf(tot), 1e-12f);
  cnT[t * 80 + n] = v / dn;
}

// ---------------- K0b: W prep: bf16 k-sliced [k][o][32] + W^T f32 -------------
__global__ __launch_bounds__(256) void k0_wprep(const float* __restrict__ fcw,
                                                unsigned short* __restrict__ wks,
                                                float* __restrict__ wt) {
  int o = blockIdx.x, c = threadIdx.x;
  float w = fcw[o * 256 + c];
  wt[c * 256 + o] = w;
  wks[((c >> 5) * 256 + o) * 32 + (c & 31)] = f2b(w);
}

// ------- K1: argmax (f32) + fsq + counts + featbf write (pixel-major) ---------
__global__ __launch_bounds__(256) void k1_argmax(const float* __restrict__ feat,
                                                 const float* __restrict__ cnT,
                                                 u8* __restrict__ idxb,
                                                 float* __restrict__ fsqg,
                                                 int* __restrict__ cntg,
                                                 unsigned short* __restrict__ featbf) {
  __shared__ int lh[80];
  int t = threadIdx.x;
  if (t < 80) lh[t] = 0;
  __syncthreads();
  int b = blockIdx.x >> 6;
  int pi = ((blockIdx.x & 63) << 8) | t;
  const float* fb = feat + (size_t)b * 256 * 16384 + pi;
  unsigned short* fo = featbf + ((size_t)b * 16384 + pi) * 256;  // own 512B row
  float g[80];
  #pragma unroll
  for (int n = 0; n < 80; ++n) g[n] = 0.f;
  float fsq = 0.f;
  for (int c8 = 0; c8 < 256; c8 += 8) {
    unsigned pk[4];
    #pragma unroll
    for (int e = 0; e < 8; ++e) {
      float v = fb[(size_t)(c8 + e) * 16384];
      fsq = fmaf(v, v, fsq);
      const float* cr = cnT + (c8 + e) * 80;
      #pragma unroll
      for (int n = 0; n < 80; ++n) g[n] = fmaf(v, cr[n], g[n]);
      unsigned short h = f2b(v);
      if (e & 1) pk[e >> 1] |= ((unsigned)h << 16); else pk[e >> 1] = h;
    }
    *(uint4*)&fo[c8] = *(const uint4*)pk;        // 16B store, sector-aligned
  }
  float best = g[0]; int bi = 0;
  #pragma unroll
  for (int n = 1; n < 80; ++n) if (g[n] > best) { best = g[n]; bi = n; }
  idxb[b * 16384 + pi] = (u8)bi;
  fsqg[b * 16384 + pi] = fsq;
  atomicAdd(&lh[bi], 1);
  __syncthreads();
  if (t < 80) atomicAdd(&cntg[b * 80 + t], lh[t]);
}

// ---------------- K1b: sumx = onehot(idx) * feat^T via MFMA (split-K=4) -------
__global__ __launch_bounds__(256) void k1b_gemm(const float* __restrict__ feat,
                                                const u8* __restrict__ idxb,
                                                unsigned short* __restrict__ sumxp) {
  int bid = blockIdx.x;
  int kp = bid & 3, ns = (bid >> 2) & 7, b = bid >> 5;
  int t = threadIdx.x, wv = t >> 6, ln = t & 63, lo = ln & 15, hi = ln >> 4;
  int nt = wv & 1;
  int m0 = (wv >> 1) ? 3 : 0, nm = (wv >> 1) ? 2 : 3;
  int c = ns * 32 + nt * 16 + lo;
  const float* fp = feat + (((size_t)b * 256 + c) * 16384 + kp * 4096 + hi * 8);
  const u8* ip = idxb + b * 16384 + kp * 4096 + hi * 8;
  f32x4 acc[3];
  f32x4 zz = {0.f, 0.f, 0.f, 0.f};
  acc[0] = zz; acc[1] = zz; acc[2] = zz;
  for (int ks = 0; ks < 128; ++ks) {
    float4 v0 = *(const float4*)(fp + ks * 32);
    float4 v1 = *(const float4*)(fp + ks * 32 + 4);
    union { unsigned short u[8]; bf16x8 v; } bb;
    bb.u[0] = f2b(v0.x); bb.u[1] = f2b(v0.y); bb.u[2] = f2b(v0.z); bb.u[3] = f2b(v0.w);
    bb.u[4] = f2b(v1.x); bb.u[5] = f2b(v1.y); bb.u[6] = f2b(v1.z); bb.u[7] = f2b(v1.w);
    uint2 iv = *(const uint2*)(ip + ks * 32);
    int id[8];
    #pragma unroll
    for (int j = 0; j < 4; ++j) { id[j] = (iv.x >> (8 * j)) & 255; id[4 + j] = (iv.y >> (8 * j)) & 255; }
    #pragma unroll
    for (int mi = 0; mi < 3; ++mi) {
      if (mi >= nm) break;
      int row = (m0 + mi) * 16 + lo;
      union { unsigned short u[8]; bf16x8 v; } ma;
      #pragma unroll
      for (int j = 0; j < 8; ++j) ma.u[j] = (id[j] == row) ? (unsigned short)0x3F80 : (unsigned short)0;
      acc[mi] = __builtin_amdgcn_mfma_f32_16x16x32_bf16(ma.v, bb.v, acc[mi], 0, 0, 0);
    }
  }
  #pragma unroll
  for (int mi = 0; mi < 3; ++mi) {
    if (mi >= nm) break;
    #pragma unroll
    for (int r = 0; r < 4; ++r) {
      int cls = (m0 + mi) * 16 + hi * 4 + r;
      sumxp[(((size_t)kp * 16 + b) * 80 + cls) * 256 + ns * 32 + nt * 16 + lo] = f2b(acc[mi][r]);
    }
  }
}

// ---------------- K2: cent = sum/max(cnt,1); csq; centf bf16; chat = W*cent ---
__global__ __launch_bounds__(256) void k2_cent(const unsigned short* __restrict__ sumxp,
                                               const int* __restrict__ cntg,
                                               const float* __restrict__ wt,
                                               unsigned short* __restrict__ centf,
                                               float* __restrict__ csqg,
                                               float* __restrict__ chatg) {
  int bn = blockIdx.x; int t = threadIdx.x;
  float dn = fmaxf((float)cntg[bn], 1.0f);
  float s = 0.f;
  #pragma unroll
  for (int kp = 0; kp < 4; ++kp)
    s += b2f(sumxp[((size_t)kp * 1280 + bn) * 256 + t]);   // [kp][b][n][c]
  float cv = s / dn;
  __shared__ float cl[256];
  __shared__ float red[4];
  cl[t] = cv;
  centf[(size_t)bn * 256 + t] = f2b(cv);
  float q = cv * cv;
  #pragma unroll
  for (int o = 32; o > 0; o >>= 1) q += __shfl_down(q, o, 64);
  if ((t & 63) == 0) red[t >> 6] = q;
  __syncthreads();
  if (t == 0) csqg[bn] = red[0] + red[1] + red[2] + red[3];
  float acc = 0.f;
  #pragma unroll 4
  for (int c = 0; c < 256; ++c) acc = fmaf(wt[c * 256 + t], cl[c], acc);
  chatg[(size_t)bn * 256 + t] = acc;
}

// ---------------- K3b: pipelined W-in-registers MFMA GEMM + alpha + epilogue --
__global__ __launch_bounds__(512) void k3b_gemm(const unsigned short* __restrict__ featbf,
    const u8* __restrict__ idxb, const float* __restrict__ fsqg,
    const float* __restrict__ csqg, const unsigned short* __restrict__ centf,
    const float* __restrict__ chatg, const unsigned short* __restrict__ wks,
    const float* __restrict__ fcb, float* __restrict__ out) {
  __shared__ alignas(16) unsigned short featT[2][64 * 264];  // double-buffered
  __shared__ float alphal[64];
  const int t = threadIdx.x;
  const int w = t >> 6, ln = t & 63, lo = ln & 15, hi = ln >> 4;
  const int spx = t >> 3, ssub = t & 7;   // staging role: pixel, 32-ch group

  bf16x8 wf[2][8];
  #pragma unroll
  for (int ml = 0; ml < 2; ++ml)
    #pragma unroll
    for (int ks = 0; ks < 8; ++ks)
      wf[ml][ks] = *(const bf16x8*)&wks[((size_t)ks * 256 + (w * 2 + ml) * 16 + lo) * 32 + hi * 8];
  f32x4 bias2[2];
  #pragma unroll
  for (int ml = 0; ml < 2; ++ml)
    bias2[ml] = *(const f32x4*)&fcb[w * 32 + ml * 16 + hi * 4];

  const int tile0 = blockIdx.x * 8;
  { // prologue: stage tile0 into buf 0 — 32KB contiguous, 16B/lane
    int b = tile0 >> 8, p0 = (tile0 & 255) << 6;
    const uint4* src = (const uint4*)(featbf + ((size_t)b * 16384 + p0 + spx) * 256 + ssub * 32);
    #pragma unroll
    for (int j = 0; j < 4; ++j)
      *(uint4*)&featT[0][spx * 264 + ssub * 32 + j * 8] = src[j];
  }

  uint4 nx[4];
  for (int rep = 0; rep < 8; ++rep) {
    const int cur = rep & 1;
    const int tile = tile0 + rep;
    const int b = tile >> 8, p0 = (tile & 255) << 6;

    __syncthreads();   // buf[cur] staged

    // issue next tile's loads now — overlap with alpha+MFMA
    if (rep < 7) {
      int t2 = tile + 1;
      int b2 = t2 >> 8, p02 = (t2 & 255) << 6;
      const uint4* src = (const uint4*)(featbf + ((size_t)b2 * 16384 + p02 + spx) * 256 + ssub * 32);
      #pragma unroll
      for (int j = 0; j < 4; ++j) nx[j] = src[j];
    }

    { // fused alpha: 8 threads per pixel over featT[cur]
      int p = spx, sub = ssub;
      int cid = idxb[b * 16384 + p0 + p];
      const unsigned short* cw = centf + ((size_t)b * 80 + cid) * 256 + sub * 32;
      const unsigned short* fr = &featT[cur][p * 264 + sub * 32];
      float sel = 0.f;
      #pragma unroll
      for (int j = 0; j < 4; ++j) {
        uint4 cc = *(const uint4*)&cw[j * 8];
        uint4 ff = *(const uint4*)&fr[j * 8];
        sel = fmaf(b2f((unsigned short)(ff.x & 0xffff)), b2f((unsigned short)(cc.x & 0xffff)), sel);
        sel = fmaf(b2f((unsigned short)(ff.x >> 16)),    b2f((unsigned short)(cc.x >> 16)),    sel);
        sel = fmaf(b2f((unsigned short)(ff.y & 0xffff)), b2f((unsigned short)(cc.y & 0xffff)), sel);
        sel = fmaf(b2f((unsigned short)(ff.y >> 16)),    b2f((unsigned short)(cc.y >> 16)),    sel);
        sel = fmaf(b2f((unsigned short)(ff.z & 0xffff)), b2f((unsigned short)(cc.z & 0xffff)), sel);
        sel = fmaf(b2f((unsigned short)(ff.z >> 16)),    b2f((unsigned short)(cc.z >> 16)),    sel);
        sel = fmaf(b2f((unsigned short)(ff.w & 0xffff)), b2f((unsigned short)(cc.w & 0xffff)), sel);
        sel = fmaf(b2f((unsigned short)(ff.w >> 16)),    b2f((unsigned short)(cc.w >> 16)),    sel);
      }
      sel += __shfl_xor(sel, 1, 64);
      sel += __shfl_xor(sel, 2, 64);
      sel += __shfl_xor(sel, 4, 64);
      if (sub == 0) {
        float fsq = fsqg[b * 16384 + p0 + p];
        float msq = (csqg[b * 80 + cid] - 2.f * sel + fsq) * (1.f / 256.f);
        alphal[p] = expf(-msq);
      }
    }

    f32x4 acc[2][4];
    f32x4 zz = {0.f, 0.f, 0.f, 0.f};
    #pragma unroll
    for (int ml = 0; ml < 2; ++ml)
      #pragma unroll
      for (int pt = 0; pt < 4; ++pt) acc[ml][pt] = zz;

    #pragma unroll
    for (int ks = 0; ks < 8; ++ks) {
      bf16x8 bfr[4];
      #pragma unroll
      for (int pt = 0; pt < 4; ++pt)
        bfr[pt] = *(const bf16x8*)&featT[cur][(pt * 16 + lo) * 264 + ks * 32 + hi * 8];
      #pragma unroll
      for (int ml = 0; ml < 2; ++ml)
        #pragma unroll
        for (int pt = 0; pt < 4; ++pt)
          acc[ml][pt] = __builtin_amdgcn_mfma_f32_16x16x32_bf16(wf[ml][ks], bfr[pt], acc[ml][pt], 0, 0, 0);
    }
    __syncthreads();   // alphal ready; featT[cur] reads done; nx loads drained

    // epilogue: blend + relu + store
    #pragma unroll
    for (int pt = 0; pt < 4; ++pt) {
      int plx = pt * 16 + lo;
      int p = p0 + plx;
      float a = alphal[plx];
      float om = 1.f - a;
      int cid = idxb[b * 16384 + p];
      const float* crow = chatg + ((size_t)b * 80 + cid) * 256;
      #pragma unroll
      for (int ml = 0; ml < 2; ++ml) {
        int o0 = w * 32 + ml * 16 + hi * 4;
        float4 c4 = *(const float4*)&crow[o0];
        size_t ob = ((size_t)b * 256 + o0) * 16384 + p;
        out[ob            ] = fmaxf(fmaf(a, c4.x, om * acc[ml][pt][0]) + bias2[ml][0], 0.f);
        out[ob + 16384    ] = fmaxf(fmaf(a, c4.y, om * acc[ml][pt][1]) + bias2[ml][1], 0.f);
        out[ob + 2 * 16384] = fmaxf(fmaf(a, c4.z, om * acc[ml][pt][2]) + bias2[ml][2], 0.f);
        out[ob + 3 * 16384] = fmaxf(fmaf(a, c4.w, om * acc[ml][pt][3]) + bias2[ml][3], 0.f);
      }
    }

    // stage next tile into buf[cur^1]
    if (rep < 7) {
      #pragma unroll
      for (int j = 0; j < 4; ++j)
        *(uint4*)&featT[cur ^ 1][spx * 264 + ssub * 32 + j * 8] = nx[j];
    }
  }
}

extern "C" void kernel_launch(void* const* d_in, const int* in_sizes, int n_in,
                              void* d_out, int out_size, void* d_ws, size_t ws_size,
                              hipStream_t stream) {
  (void)in_sizes; (void)n_in; (void)out_size; (void)ws_size;
  const float* feat = (const float*)d_in[0];
  const float* cent = (const float*)d_in[1];
  const float* fcw  = (const float*)d_in[2];
  const float* fcb  = (const float*)d_in[3];
  float* out = (float*)d_out;
  char* ws = (char*)d_ws;
  unsigned short* featbf = (unsigned short*)(ws);
  float* cnT             = (float*)(ws + 134217728);
  float* wt              = (float*)(ws + 134299648);
  unsigned short* wks    = (unsigned short*)(ws + 134561792);
  unsigned short* centf  = (unsigned short*)(ws + 134692864);
  u8*    idxb            = (u8*)(ws + 135348224);
  float* fsq             = (float*)(ws + 135610368);
  int*   cntg            = (int*)(ws + 136658944);
  float* csq             = (float*)(ws + 136664064);
  float* chat            = (float*)(ws + 136669184);
  unsigned short* sumxp  = (unsigned short*)(ws + 137979904);

  k0_cnorm<<<80, 256, 0, stream>>>(cent, cnT, cntg);
  k0_wprep<<<256, 256, 0, stream>>>(fcw, wks, wt);
  k1_argmax<<<1024, 256, 0, stream>>>(feat, cnT, idxb, fsq, cntg, featbf);
  k1b_gemm<<<512, 256, 0, stream>>>(feat, idxb, sumxp);
  k2_cent<<<1280, 256, 0, stream>>>(sumxp, cntg, wt, centf, csq, chat);
  k3b_gemm<<<512, 512, 0, stream>>>(featbf, idxb, fsq, csq, centf, chat, wks, fcb, out);
}

// Round 10
// 490.496 us; speedup vs baseline: 1.3502x; 1.3502x over previous
//
#include <hip/hip_runtime.h>

// Refine: out = relu((1-a)*(W f) + a*chat[idx] + bias)
// a = exp(-(csq - 2*<f,cent[idx]> + fsq)/256), chat = W*cent
// idx = argmax_n <f, cnorm_n>
//
// ws layout (1 GiB available; ~88 MB used):
//  cnT    [256][80] f32        @ 0
//  wt     [256][256] f32       @ 81920
//  wks    [8][256][32] bf16    @ 344064
//  centf  [16][80][256] bf16   @ 475136
//  idxb   [16*16384] u8        @ 1130496
//  fsq    [16*16384] f32       @ 1392640
//  cnt    [16*80] i32          @ 2441216  (zeroed by k0_cnorm)
//  csq    [16*80] f32          @ 2446336
//  chat   [16][80][256] f32    @ 2451456
//  part   [16][64][80][256] f32 @ 3762176  (per-block sumx partials, NON-atomic)

typedef __bf16 bf16x8 __attribute__((ext_vector_type(8)));
typedef float  f32x4  __attribute__((ext_vector_type(4)));
typedef unsigned char u8;

__device__ __forceinline__ unsigned short f2b(float f) {
  unsigned u = __float_as_uint(f);
  return (unsigned short)((u + 0x7fffu + ((u >> 16) & 1u)) >> 16);
}
__device__ __forceinline__ float b2f(unsigned short s) {
  return __uint_as_float((unsigned)s << 16);
}

// ---------------- K0a: normalized centroids [c][n] + zero cntg ----------------
__global__ __launch_bounds__(256) void k0_cnorm(const float* __restrict__ cent,
                                                float* __restrict__ cnT,
                                                int* __restrict__ cntg) {
  int n = blockIdx.x, t = threadIdx.x;
  if (t < 16) cntg[n * 16 + t] = 0;
  float v = cent[n * 256 + t];
  float s = v * v;
  #pragma unroll
  for (int o = 32; o > 0; o >>= 1) s += __shfl_down(s, o, 64);
  __shared__ float red[4];
  if ((t & 63) == 0) red[t >> 6] = s;
  __syncthreads();
  float tot = red[0] + red[1] + red[2] + red[3];
  float dn = fmaxf(sqrtf(tot), 1e-12f);
  cnT[t * 80 + n] = v / dn;
}

// ---------------- K0b: W prep: bf16 k-sliced [k][o][32] + W^T f32 -------------
__global__ __launch_bounds__(256) void k0_wprep(const float* __restrict__ fcw,
                                                unsigned short* __restrict__ wks,
                                                float* __restrict__ wt) {
  int o = blockIdx.x, c = threadIdx.x;
  float w = fcw[o * 256 + c];
  wt[c * 256 + o] = w;
  wks[((c >> 5) * 256 + o) * 32 + (c & 31)] = f2b(w);
}

// ---- K1F: argmax (f32, exact) + fsq + counts + one-hot MFMA sumx partial -----
__global__ __launch_bounds__(256) void k1f(const float* __restrict__ feat,
                                           const float* __restrict__ cnT,
                                           u8* __restrict__ idxb,
                                           float* __restrict__ fsqg,
                                           int* __restrict__ cntg,
                                           float* __restrict__ part) {
  __shared__ alignas(8) u8 idxl[256];
  __shared__ int lh[80];
  const int b = blockIdx.x >> 6, chunk = blockIdx.x & 63;
  const int px0 = chunk << 8;
  const int t = threadIdx.x, wv = t >> 6, ln = t & 63, lo = ln & 15, hi = ln >> 4;
  if (t < 80) lh[t] = 0;
  __syncthreads();

  // ---- argmax phase: EXACT code/order of the proven k1 (identical idx) ----
  const int pi = px0 | t;
  const float* fb = feat + (size_t)b * 256 * 16384 + pi;
  float g[80];
  #pragma unroll
  for (int n = 0; n < 80; ++n) g[n] = 0.f;
  float fsq = 0.f;
  #pragma unroll 4
  for (int c = 0; c < 256; ++c) {
    float v = fb[(size_t)c * 16384];
    fsq = fmaf(v, v, fsq);
    const float* cr = cnT + c * 80;
    #pragma unroll
    for (int n = 0; n < 80; ++n) g[n] = fmaf(v, cr[n], g[n]);
  }
  float best = g[0]; int bi = 0;
  #pragma unroll
  for (int n = 1; n < 80; ++n) if (g[n] > best) { best = g[n]; bi = n; }
  idxb[b * 16384 + pi] = (u8)bi;
  fsqg[b * 16384 + pi] = fsq;
  idxl[t] = (u8)bi;
  atomicAdd(&lh[bi], 1);
  __syncthreads();
  if (t < 80) atomicAdd(&cntg[b * 80 + t], lh[t]);

  // ---- sumx phase: one-hot MFMA over this block's 256 px (feat L3-hot) ----
  f32x4 acc[5][4];
  f32x4 zz = {0.f, 0.f, 0.f, 0.f};
  #pragma unroll
  for (int mt = 0; mt < 5; ++mt)
    #pragma unroll
    for (int nt = 0; nt < 4; ++nt) acc[mt][nt] = zz;
  const int chb = wv * 64;
  #pragma unroll 2
  for (int ks = 0; ks < 8; ++ks) {
    uint2 iv = *(const uint2*)&idxl[ks * 32 + hi * 8];
    int id[8];
    #pragma unroll
    for (int j = 0; j < 4; ++j) { id[j] = (iv.x >> (8 * j)) & 255; id[4 + j] = (iv.y >> (8 * j)) & 255; }
    bf16x8 bfr[4];
    #pragma unroll
    for (int nt = 0; nt < 4; ++nt) {
      const float* bp = feat + ((size_t)b * 256 + chb + nt * 16 + lo) * 16384 + px0 + ks * 32 + hi * 8;
      float4 v0 = *(const float4*)bp;
      float4 v1 = *(const float4*)(bp + 4);
      union { unsigned short u[8]; bf16x8 v; } bb;
      bb.u[0] = f2b(v0.x); bb.u[1] = f2b(v0.y); bb.u[2] = f2b(v0.z); bb.u[3] = f2b(v0.w);
      bb.u[4] = f2b(v1.x); bb.u[5] = f2b(v1.y); bb.u[6] = f2b(v1.z); bb.u[7] = f2b(v1.w);
      bfr[nt] = bb.v;
    }
    #pragma unroll
    for (int mt = 0; mt < 5; ++mt) {
      int row = mt * 16 + lo;
      union { unsigned short u[8]; bf16x8 v; } ma;
      #pragma unroll
      for (int j = 0; j < 8; ++j) ma.u[j] = (id[j] == row) ? (unsigned short)0x3F80 : (unsigned short)0;
      #pragma unroll
      for (int nt = 0; nt < 4; ++nt)
        acc[mt][nt] = __builtin_amdgcn_mfma_f32_16x16x32_bf16(ma.v, bfr[nt], acc[mt][nt], 0, 0, 0);
    }
  }
  // block-owned partial write: NO atomics, coalesced 64B sectors
  float* pb = part + ((size_t)(b * 64 + chunk) * 80) * 256;
  #pragma unroll
  for (int mt = 0; mt < 5; ++mt)
    #pragma unroll
    for (int nt = 0; nt < 4; ++nt)
      #pragma unroll
      for (int r = 0; r < 4; ++r)
        pb[(mt * 16 + hi * 4 + r) * 256 + chb + nt * 16 + lo] = acc[mt][nt][r];
}

// -------- K2: cent = Σ64 partials / max(cnt,1); csq; centf; chat = W*cent -----
__global__ __launch_bounds__(256) void k2_cent(const float* __restrict__ part,
                                               const int* __restrict__ cntg,
                                               const float* __restrict__ wt,
                                               unsigned short* __restrict__ centf,
                                               float* __restrict__ csqg,
                                               float* __restrict__ chatg) {
  int bn = blockIdx.x; int b = bn / 80, n = bn - b * 80; int t = threadIdx.x;
  float dn = fmaxf((float)cntg[bn], 1.0f);
  float s = 0.f;
  const float* pp = part + ((size_t)(b * 64) * 80 + n) * 256 + t;
  #pragma unroll 8
  for (int ck = 0; ck < 64; ++ck) s += pp[(size_t)ck * 80 * 256];
  float cv = s / dn;
  __shared__ float cl[256];
  __shared__ float red[4];
  cl[t] = cv;
  centf[(size_t)bn * 256 + t] = f2b(cv);
  float q = cv * cv;
  #pragma unroll
  for (int o = 32; o > 0; o >>= 1) q += __shfl_down(q, o, 64);
  if ((t & 63) == 0) red[t >> 6] = q;
  __syncthreads();
  if (t == 0) csqg[bn] = red[0] + red[1] + red[2] + red[3];
  float acc = 0.f;
  #pragma unroll 4
  for (int c = 0; c < 256; ++c) acc = fmaf(wt[c * 256 + t], cl[c], acc);
  chatg[(size_t)bn * 256 + t] = acc;
}

// ---------------- K3b: pipelined W-in-registers MFMA GEMM + alpha + epilogue --
__global__ __launch_bounds__(512) void k3b_gemm(const float* __restrict__ feat,
    const u8* __restrict__ idxb, const float* __restrict__ fsqg,
    const float* __restrict__ csqg, const unsigned short* __restrict__ centf,
    const float* __restrict__ chatg, const unsigned short* __restrict__ wks,
    const float* __restrict__ fcb, float* __restrict__ out) {
  __shared__ alignas(16) unsigned short featT[2][64 * 264];  // double-buffered
  __shared__ float alphal[64];
  __shared__ int cidl[64];
  const int t = threadIdx.x;
  const int w = t >> 6, ln = t & 63, lo = ln & 15, hi = ln >> 4;
  const int pl = ln, cph = w;   // staging role: pixel, 32-ch group

  bf16x8 wf[2][8];
  #pragma unroll
  for (int ml = 0; ml < 2; ++ml)
    #pragma unroll
    for (int ks = 0; ks < 8; ++ks)
      wf[ml][ks] = *(const bf16x8*)&wks[((size_t)ks * 256 + (w * 2 + ml) * 16 + lo) * 32 + hi * 8];
  f32x4 bias2[2];
  #pragma unroll
  for (int ml = 0; ml < 2; ++ml)
    bias2[ml] = *(const f32x4*)&fcb[w * 32 + ml * 16 + hi * 4];

  const int tile0 = blockIdx.x * 8;
  { // prologue: stage tile0 into buf 0
    int b = tile0 >> 8, p0 = (tile0 & 255) << 6;
    const float* fb = feat + ((size_t)b * 256 + cph * 32) * 16384 + p0 + pl;
    #pragma unroll
    for (int jj = 0; jj < 4; ++jj) {
      union { unsigned short u[8]; uint4 q; } pk;
      #pragma unroll
      for (int e = 0; e < 8; ++e) pk.u[e] = f2b(fb[(size_t)(jj * 8 + e) * 16384]);
      *(uint4*)&featT[0][pl * 264 + cph * 32 + jj * 8] = pk.q;
    }
  }

  float nxv[32];
  for (int rep = 0; rep < 8; ++rep) {
    const int cur = rep & 1;
    const int tile = tile0 + rep;
    const int b = tile >> 8, p0 = (tile & 255) << 6;

    __syncthreads();   // buf[cur] staged

    // issue next tile's loads now — overlap with alpha+MFMA
    if (rep < 7) {
      int t2 = tile + 1;
      int b2 = t2 >> 8, p02 = (t2 & 255) << 6;
      const float* fb2 = feat + ((size_t)b2 * 256 + cph * 32) * 16384 + p02 + pl;
      #pragma unroll
      for (int e = 0; e < 32; ++e) nxv[e] = fb2[(size_t)e * 16384];
    }

    { // fused alpha: 8 threads per pixel over featT[cur]
      int p = t >> 3, sub = t & 7;
      int cid = idxb[b * 16384 + p0 + p];
      const unsigned short* cw = centf + ((size_t)b * 80 + cid) * 256 + sub * 32;
      const unsigned short* fr = &featT[cur][p * 264 + sub * 32];
      float sel = 0.f;
      #pragma unroll
      for (int j = 0; j < 4; ++j) {
        uint4 cc = *(const uint4*)&cw[j * 8];
        uint4 ff = *(const uint4*)&fr[j * 8];
        sel = fmaf(b2f((unsigned short)(ff.x & 0xffff)), b2f((unsigned short)(cc.x & 0xffff)), sel);
        sel = fmaf(b2f((unsigned short)(ff.x >> 16)),    b2f((unsigned short)(cc.x >> 16)),    sel);
        sel = fmaf(b2f((unsigned short)(ff.y & 0xffff)), b2f((unsigned short)(cc.y & 0xffff)), sel);
        sel = fmaf(b2f((unsigned short)(ff.y >> 16)),    b2f((unsigned short)(cc.y >> 16)),    sel);
        sel = fmaf(b2f((unsigned short)(ff.z & 0xffff)), b2f((unsigned short)(cc.z & 0xffff)), sel);
        sel = fmaf(b2f((unsigned short)(ff.z >> 16)),    b2f((unsigned short)(cc.z >> 16)),    sel);
        sel = fmaf(b2f((unsigned short)(ff.w & 0xffff)), b2f((unsigned short)(cc.w & 0xffff)), sel);
        sel = fmaf(b2f((unsigned short)(ff.w >> 16)),    b2f((unsigned short)(cc.w >> 16)),    sel);
      }
      sel += __shfl_xor(sel, 1, 64);
      sel += __shfl_xor(sel, 2, 64);
      sel += __shfl_xor(sel, 4, 64);
      if (sub == 0) {
        float fsq = fsqg[b * 16384 + p0 + p];
        float msq = (csqg[b * 80 + cid] - 2.f * sel + fsq) * (1.f / 256.f);
        alphal[p] = expf(-msq);
        cidl[p] = cid;
      }
    }

    f32x4 acc[2][4];
    f32x4 zz = {0.f, 0.f, 0.f, 0.f};
    #pragma unroll
    for (int ml = 0; ml < 2; ++ml)
      #pragma unroll
      for (int pt = 0; pt < 4; ++pt) acc[ml][pt] = zz;

    #pragma unroll
    for (int ks = 0; ks < 8; ++ks) {
      bf16x8 bfr[4];
      #pragma unroll
      for (int pt = 0; pt < 4; ++pt)
        bfr[pt] = *(const bf16x8*)&featT[cur][(pt * 16 + lo) * 264 + ks * 32 + hi * 8];
      #pragma unroll
      for (int ml = 0; ml < 2; ++ml)
        #pragma unroll
        for (int pt = 0; pt < 4; ++pt)
          acc[ml][pt] = __builtin_amdgcn_mfma_f32_16x16x32_bf16(wf[ml][ks], bfr[pt], acc[ml][pt], 0, 0, 0);
    }
    __syncthreads();   // alphal/cidl ready; featT[cur] reads done; nxv drained

    // epilogue: blend + relu + store (cid/alpha from LDS)
    #pragma unroll
    for (int pt = 0; pt < 4; ++pt) {
      int plx = pt * 16 + lo;
      int p = p0 + plx;
      float a = alphal[plx];
      float om = 1.f - a;
      const float* crow = chatg + ((size_t)b * 80 + cidl[plx]) * 256;
      #pragma unroll
      for (int ml = 0; ml < 2; ++ml) {
        int o0 = w * 32 + ml * 16 + hi * 4;
        float4 c4 = *(const float4*)&crow[o0];
        size_t ob = ((size_t)b * 256 + o0) * 16384 + p;
        out[ob            ] = fmaxf(fmaf(a, c4.x, om * acc[ml][pt][0]) + bias2[ml][0], 0.f);
        out[ob + 16384    ] = fmaxf(fmaf(a, c4.y, om * acc[ml][pt][1]) + bias2[ml][1], 0.f);
        out[ob + 2 * 16384] = fmaxf(fmaf(a, c4.z, om * acc[ml][pt][2]) + bias2[ml][2], 0.f);
        out[ob + 3 * 16384] = fmaxf(fmaf(a, c4.w, om * acc[ml][pt][3]) + bias2[ml][3], 0.f);
      }
    }

    // stage next tile into buf[cur^1]
    if (rep < 7) {
      #pragma unroll
      for (int jj = 0; jj < 4; ++jj) {
        union { unsigned short u[8]; uint4 q; } pk;
        #pragma unroll
        for (int e = 0; e < 8; ++e) pk.u[e] = f2b(nxv[jj * 8 + e]);
        *(uint4*)&featT[cur ^ 1][pl * 264 + cph * 32 + jj * 8] = pk.q;
      }
    }
  }
}

extern "C" void kernel_launch(void* const* d_in, const int* in_sizes, int n_in,
                              void* d_out, int out_size, void* d_ws, size_t ws_size,
                              hipStream_t stream) {
  (void)in_sizes; (void)n_in; (void)out_size; (void)ws_size;
  const float* feat = (const float*)d_in[0];
  const float* cent = (const float*)d_in[1];
  const float* fcw  = (const float*)d_in[2];
  const float* fcb  = (const float*)d_in[3];
  float* out = (float*)d_out;
  char* ws = (char*)d_ws;
  float* cnT             = (float*)(ws);
  float* wt              = (float*)(ws + 81920);
  unsigned short* wks    = (unsigned short*)(ws + 344064);
  unsigned short* centf  = (unsigned short*)(ws + 475136);
  u8*    idxb            = (u8*)(ws + 1130496);
  float* fsq             = (float*)(ws + 1392640);
  int*   cntg            = (int*)(ws + 2441216);
  float* csq             = (float*)(ws + 2446336);
  float* chat            = (float*)(ws + 2451456);
  float* part            = (float*)(ws + 3762176);

  k0_cnorm<<<80, 256, 0, stream>>>(cent, cnT, cntg);
  k0_wprep<<<256, 256, 0, stream>>>(fcw, wks, wt);
  k1f<<<1024, 256, 0, stream>>>(feat, cnT, idxb, fsq, cntg, part);
  k2_cent<<<1280, 256, 0, stream>>>(part, cntg, wt, centf, csq, chat);
  k3b_gemm<<<512, 512, 0, stream>>>(feat, idxb, fsq, csq, centf, chat, wks, fcb, out);
}

// Round 12
// 489.488 us; speedup vs baseline: 1.3529x; 1.0021x over previous
//
#include <hip/hip_runtime.h>

// Refine: out = relu((1-a)*(W f) + a*chat[idx] + bias)
// a = exp(-(csq - 2*<f,cent[idx]> + fsq)/256), chat = W*cent
// idx = argmax_n <f, cnorm_n>  — split-bf16 MFMA sim + exact-f32 fallback on near-ties
//
// ws layout (1 GiB available; ~88 MB used):
//  cnksh  [8][80][32] bf16     @ 0        (cnorm hi k-slices)
//  cnksl  [8][80][32] bf16     @ 40960    (cnorm lo k-slices)
//  cnT    [256][80] f32        @ 81920    (exact cnorm for fallback)
//  wt     [256][256] f32       @ 163840
//  wks    [8][256][32] bf16    @ 425984
//  centf  [16][80][256] bf16   @ 557056
//  idxb   [16*16384] u8        @ 1212416
//  fsq    [16*16384] f32       @ 1474560
//  cnt    [16*80] i32          @ 2523136  (zeroed by k0_cnorm)
//  csq    [16*80] f32          @ 2528256
//  chat   [16][80][256] f32    @ 2533376
//  part   [16][64][80][256] f32 @ 3844096 (per-block sumx partials, NON-atomic)

typedef __bf16 bf16x8 __attribute__((ext_vector_type(8)));
typedef float  f32x4  __attribute__((ext_vector_type(4)));
typedef unsigned char u8;

__device__ __forceinline__ unsigned short f2b(float f) {
  unsigned u = __float_as_uint(f);
  return (unsigned short)((u + 0x7fffu + ((u >> 16) & 1u)) >> 16);
}
__device__ __forceinline__ float b2f(unsigned short s) {
  return __uint_as_float((unsigned)s << 16);
}

// -- K0a: normalized centroids -> f32 table + bf16 hi/lo k-slices + zero cntg --
__global__ __launch_bounds__(256) void k0_cnorm(const float* __restrict__ cent,
                                                unsigned short* __restrict__ cnksh,
                                                unsigned short* __restrict__ cnksl,
                                                float* __restrict__ cnT,
                                                int* __restrict__ cntg) {
  int n = blockIdx.x, t = threadIdx.x;
  if (t < 16) cntg[n * 16 + t] = 0;
  float v = cent[n * 256 + t];
  float s = v * v;
  #pragma unroll
  for (int o = 32; o > 0; o >>= 1) s += __shfl_down(s, o, 64);
  __shared__ float red[4];
  if ((t & 63) == 0) red[t >> 6] = s;
  __syncthreads();
  float tot = red[0] + red[1] + red[2] + red[3];
  float dn = fmaxf(sqrtf(tot), 1e-12f);
  float val = v / dn;
  cnT[t * 80 + n] = val;
  unsigned short h = f2b(val);
  int slot = ((t >> 5) * 80 + n) * 32 + (t & 31);
  cnksh[slot] = h;
  cnksl[slot] = f2b(val - b2f(h));
}

// ---------------- K0b: W prep: bf16 k-sliced [k][o][32] + W^T f32 -------------
__global__ __launch_bounds__(256) void k0_wprep(const float* __restrict__ fcw,
                                                unsigned short* __restrict__ wks,
                                                float* __restrict__ wt) {
  int o = blockIdx.x, c = threadIdx.x;
  float w = fcw[o * 256 + c];
  wt[c * 256 + o] = w;
  wks[((c >> 5) * 256 + o) * 32 + (c & 31)] = f2b(w);
}

// ---- K1F: split-MFMA argmax (+f32 fallback) + fsq + counts + sumx partial ----
__global__ __launch_bounds__(256) void k1f(const float* __restrict__ feat,
                                           const unsigned short* __restrict__ cnksh,
                                           const unsigned short* __restrict__ cnksl,
                                           const float* __restrict__ cnT,
                                           u8* __restrict__ idxb,
                                           float* __restrict__ fsqg,
                                           int* __restrict__ cntg,
                                           float* __restrict__ part) {
  __shared__ alignas(8) u8 idxl[256];
  __shared__ int lh[80];
  const int b = blockIdx.x >> 6, chunk = blockIdx.x & 63;
  const int px0 = chunk << 8;
  const int t = threadIdx.x, wv = t >> 6, ln = t & 63, lo = ln & 15, hi = ln >> 4;
  const float DELTA = 2e-3f;
  if (t < 80) lh[t] = 0;
  __syncthreads();

  // ---- sim phase: 3-MFMA split-bf16 sim[class][px]; fsq f32 from same loads --
  f32x4 acc[5][4];
  f32x4 zz = {0.f, 0.f, 0.f, 0.f};
  #pragma unroll
  for (int m = 0; m < 5; ++m)
    #pragma unroll
    for (int nt = 0; nt < 4; ++nt) acc[m][nt] = zz;
  float fsqp[4] = {0.f, 0.f, 0.f, 0.f};
  const float* fbase = feat + (size_t)b * 256 * 16384 + px0 + wv * 64 + lo;

  for (int ks = 0; ks < 8; ++ks) {
    bf16x8 cah[5], cal[5];
    #pragma unroll
    for (int m = 0; m < 5; ++m) {
      size_t off = ((size_t)ks * 80 + m * 16 + lo) * 32 + hi * 8;
      cah[m] = *(const bf16x8*)&cnksh[off];
      cal[m] = *(const bf16x8*)&cnksl[off];
    }
    #pragma unroll
    for (int nt = 0; nt < 4; ++nt) {
      const float* fp = fbase + nt * 16;
      float v[8];
      #pragma unroll
      for (int j = 0; j < 8; ++j) v[j] = fp[(size_t)(ks * 32 + hi * 8 + j) * 16384];
      union { unsigned short u[8]; bf16x8 w; } bh, bl;
      #pragma unroll
      for (int j = 0; j < 8; ++j) {
        fsqp[nt] = fmaf(v[j], v[j], fsqp[nt]);
        unsigned short h = f2b(v[j]);
        bh.u[j] = h;
        bl.u[j] = f2b(v[j] - b2f(h));
      }
      #pragma unroll
      for (int m = 0; m < 5; ++m) {
        acc[m][nt] = __builtin_amdgcn_mfma_f32_16x16x32_bf16(cah[m], bh.w, acc[m][nt], 0, 0, 0);
        acc[m][nt] = __builtin_amdgcn_mfma_f32_16x16x32_bf16(cah[m], bl.w, acc[m][nt], 0, 0, 0);
        acc[m][nt] = __builtin_amdgcn_mfma_f32_16x16x32_bf16(cal[m], bh.w, acc[m][nt], 0, 0, 0);
      }
    }
  }

  // ---- per-pixel argmax: butterfly + near-tie exact-f32 fallback ----
  #pragma unroll
  for (int nt = 0; nt < 4; ++nt) {
    float best = acc[0][nt][0];
    int bi = hi * 4;
    #pragma unroll
    for (int m = 0; m < 5; ++m)
      #pragma unroll
      for (int r = 0; r < 4; ++r) {
        if (m == 0 && r == 0) continue;
        float cv = acc[m][nt][r];
        int ci = m * 16 + hi * 4 + r;
        if (cv > best) { best = cv; bi = ci; }
      }
    #pragma unroll
    for (int off = 16; off <= 32; off <<= 1) {
      float ov = __shfl_xor(best, off, 64);
      int oi = __shfl_xor(bi, off, 64);
      if (ov > best || (ov == best && oi < bi)) { best = ov; bi = oi; }
    }
    float fs = fsqp[nt];
    fs += __shfl_xor(fs, 16, 64);
    fs += __shfl_xor(fs, 32, 64);

    // candidate mask: classes within DELTA of global best
    unsigned cmask = 0;
    #pragma unroll
    for (int m = 0; m < 5; ++m)
      #pragma unroll
      for (int r = 0; r < 4; ++r)
        if (acc[m][nt][r] >= best - DELTA) cmask |= (1u << (m * 4 + r));
    int nc = __popc(cmask);
    nc += __shfl_xor(nc, 16, 64);
    nc += __shfl_xor(nc, 32, 64);
    int idx = bi;

    if (__any(nc > 1)) {  // rare (~0.7% px): exact f32 recompute of candidates
      float bv2 = -3.4e38f; int bi2 = 255;
      unsigned mm = (nc > 1) ? cmask : 0u;
      const float* fp2 = feat + (size_t)b * 256 * 16384 + px0 + wv * 64 + nt * 16 + lo;
      while (__any(mm != 0u)) {
        bool act = (mm != 0u);
        int s = act ? (__ffs(mm) - 1) : 0;
        mm &= (mm - 1);
        if (act) {
          int cls = ((s >> 2) * 16) + hi * 4 + (s & 3);
          float d = 0.f;
          #pragma unroll 4
          for (int c = 0; c < 256; ++c)
            d = fmaf(fp2[(size_t)c * 16384], cnT[c * 80 + cls], d);  // same order as proven k1
          if (d > bv2 || (d == bv2 && cls < bi2)) { bv2 = d; bi2 = cls; }
        }
      }
      #pragma unroll
      for (int off = 16; off <= 32; off <<= 1) {
        float ov = __shfl_xor(bv2, off, 64);
        int oi = __shfl_xor(bi2, off, 64);
        if (ov > bv2 || (ov == bv2 && oi < bi2)) { bv2 = ov; bi2 = oi; }
      }
      if (nc > 1) idx = bi2;
    }

    int px = wv * 64 + nt * 16 + lo;
    if (hi == 0) {
      idxl[px] = (u8)idx;
      idxb[b * 16384 + px0 + px] = (u8)idx;
      fsqg[b * 16384 + px0 + px] = fs;
      atomicAdd(&lh[idx], 1);
    }
  }
  __syncthreads();
  if (t < 80) atomicAdd(&cntg[b * 80 + t], lh[t]);

  // ---- sumx phase: one-hot MFMA over this block's 256 px (feat L2/L3-hot) ----
  #pragma unroll
  for (int mt = 0; mt < 5; ++mt)
    #pragma unroll
    for (int nt = 0; nt < 4; ++nt) acc[mt][nt] = zz;
  const int chb = wv * 64;
  #pragma unroll 2
  for (int ks = 0; ks < 8; ++ks) {
    uint2 iv = *(const uint2*)&idxl[ks * 32 + hi * 8];
    int id[8];
    #pragma unroll
    for (int j = 0; j < 4; ++j) { id[j] = (iv.x >> (8 * j)) & 255; id[4 + j] = (iv.y >> (8 * j)) & 255; }
    bf16x8 bfr[4];
    #pragma unroll
    for (int nt = 0; nt < 4; ++nt) {
      const float* bp = feat + ((size_t)b * 256 + chb + nt * 16 + lo) * 16384 + px0 + ks * 32 + hi * 8;
      float4 v0 = *(const float4*)bp;
      float4 v1 = *(const float4*)(bp + 4);
      union { unsigned short u[8]; bf16x8 v; } bb;
      bb.u[0] = f2b(v0.x); bb.u[1] = f2b(v0.y); bb.u[2] = f2b(v0.z); bb.u[3] = f2b(v0.w);
      bb.u[4] = f2b(v1.x); bb.u[5] = f2b(v1.y); bb.u[6] = f2b(v1.z); bb.u[7] = f2b(v1.w);
      bfr[nt] = bb.v;
    }
    #pragma unroll
    for (int mt = 0; mt < 5; ++mt) {
      int row = mt * 16 + lo;
      union { unsigned short u[8]; bf16x8 v; } ma;
      #pragma unroll
      for (int j = 0; j < 8; ++j) ma.u[j] = (id[j] == row) ? (unsigned short)0x3F80 : (unsigned short)0;
      #pragma unroll
      for (int nt = 0; nt < 4; ++nt)
        acc[mt][nt] = __builtin_amdgcn_mfma_f32_16x16x32_bf16(ma.v, bfr[nt], acc[mt][nt], 0, 0, 0);
    }
  }
  float* pb = part + ((size_t)(b * 64 + chunk) * 80) * 256;
  #pragma unroll
  for (int mt = 0; mt < 5; ++mt)
    #pragma unroll
    for (int nt = 0; nt < 4; ++nt)
      #pragma unroll
      for (int r = 0; r < 4; ++r)
        pb[(mt * 16 + hi * 4 + r) * 256 + chb + nt * 16 + lo] = acc[mt][nt][r];
}

// -------- K2: cent = Σ64 partials / max(cnt,1); csq; centf; chat = W*cent -----
__global__ __launch_bounds__(256) void k2_cent(const float* __restrict__ part,
                                               const int* __restrict__ cntg,
                                               const float* __restrict__ wt,
                                               unsigned short* __restrict__ centf,
                                               float* __restrict__ csqg,
                                               float* __restrict__ chatg) {
  int bn = blockIdx.x; int b = bn / 80, n = bn - b * 80; int t = threadIdx.x;
  float dn = fmaxf((float)cntg[bn], 1.0f);
  float s = 0.f;
  const float* pp = part + ((size_t)(b * 64) * 80 + n) * 256 + t;
  #pragma unroll 8
  for (int ck = 0; ck < 64; ++ck) s += pp[(size_t)ck * 80 * 256];
  float cv = s / dn;
  __shared__ float cl[256];
  __shared__ float red[4];
  cl[t] = cv;
  centf[(size_t)bn * 256 + t] = f2b(cv);
  float q = cv * cv;
  #pragma unroll
  for (int o = 32; o > 0; o >>= 1) q += __shfl_down(q, o, 64);
  if ((t & 63) == 0) red[t >> 6] = q;
  __syncthreads();
  if (t == 0) csqg[bn] = red[0] + red[1] + red[2] + red[3];
  float acc = 0.f;
  #pragma unroll 4
  for (int c = 0; c < 256; ++c) acc = fmaf(wt[c * 256 + t], cl[c], acc);
  chatg[(size_t)bn * 256 + t] = acc;
}

// ---------------- K3b: pipelined W-in-registers MFMA GEMM + alpha + epilogue --
__global__ __launch_bounds__(512) void k3b_gemm(const float* __restrict__ feat,
    const u8* __restrict__ idxb, const float* __restrict__ fsqg,
    const float* __restrict__ csqg, const unsigned short* __restrict__ centf,
    const float* __restrict__ chatg, const unsigned short* __restrict__ wks,
    const float* __restrict__ fcb, float* __restrict__ out) {
  __shared__ alignas(16) unsigned short featT[2][64 * 264];  // double-buffered
  __shared__ float alphal[64];
  __shared__ int cidl[64];
  const int t = threadIdx.x;
  const int w = t >> 6, ln = t & 63, lo = ln & 15, hi = ln >> 4;
  const int pl = ln, cph = w;   // staging role: pixel, 32-ch group

  bf16x8 wf[2][8];
  #pragma unroll
  for (int ml = 0; ml < 2; ++ml)
    #pragma unroll
    for (int ks = 0; ks < 8; ++ks)
      wf[ml][ks] = *(const bf16x8*)&wks[((size_t)ks * 256 + (w * 2 + ml) * 16 + lo) * 32 + hi * 8];
  f32x4 bias2[2];
  #pragma unroll
  for (int ml = 0; ml < 2; ++ml)
    bias2[ml] = *(const f32x4*)&fcb[w * 32 + ml * 16 + hi * 4];

  const int tile0 = blockIdx.x * 8;
  { // prologue: stage tile0 into buf 0
    int b = tile0 >> 8, p0 = (tile0 & 255) << 6;
    const float* fb = feat + ((size_t)b * 256 + cph * 32) * 16384 + p0 + pl;
    #pragma unroll
    for (int jj = 0; jj < 4; ++jj) {
      union { unsigned short u[8]; uint4 q; } pk;
      #pragma unroll
      for (int e = 0; e < 8; ++e) pk.u[e] = f2b(fb[(size_t)(jj * 8 + e) * 16384]);
      *(uint4*)&featT[0][pl * 264 + cph * 32 + jj * 8] = pk.q;
    }
  }

  float nxv[32];
  for (int rep = 0; rep < 8; ++rep) {
    const int cur = rep & 1;
    const int tile = tile0 + rep;
    const int b = tile >> 8, p0 = (tile & 255) << 6;

    __syncthreads();   // buf[cur] staged

    if (rep < 7) {
      int t2 = tile + 1;
      int b2 = t2 >> 8, p02 = (t2 & 255) << 6;
      const float* fb2 = feat + ((size_t)b2 * 256 + cph * 32) * 16384 + p02 + pl;
      #pragma unroll
      for (int e = 0; e < 32; ++e) nxv[e] = fb2[(size_t)e * 16384];
    }

    { // fused alpha: 8 threads per pixel over featT[cur]
      int p = t >> 3, sub = t & 7;
      int cid = idxb[b * 16384 + p0 + p];
      const unsigned short* cw = centf + ((size_t)b * 80 + cid) * 256 + sub * 32;
      const unsigned short* fr = &featT[cur][p * 264 + sub * 32];
      float sel = 0.f;
      #pragma unroll
      for (int j = 0; j < 4; ++j) {
        uint4 cc = *(const uint4*)&cw[j * 8];
        uint4 ff = *(const uint4*)&fr[j * 8];
        sel = fmaf(b2f((unsigned short)(ff.x & 0xffff)), b2f((unsigned short)(cc.x & 0xffff)), sel);
        sel = fmaf(b2f((unsigned short)(ff.x >> 16)),    b2f((unsigned short)(cc.x >> 16)),    sel);
        sel = fmaf(b2f((unsigned short)(ff.y & 0xffff)), b2f((unsigned short)(cc.y & 0xffff)), sel);
        sel = fmaf(b2f((unsigned short)(ff.y >> 16)),    b2f((unsigned short)(cc.y >> 16)),    sel);
        sel = fmaf(b2f((unsigned short)(ff.z & 0xffff)), b2f((unsigned short)(cc.z & 0xffff)), sel);
        sel = fmaf(b2f((unsigned short)(ff.z >> 16)),    b2f((unsigned short)(cc.z >> 16)),    sel);
        sel = fmaf(b2f((unsigned short)(ff.w & 0xffff)), b2f((unsigned short)(cc.w & 0xffff)), sel);
        sel = fmaf(b2f((unsigned short)(ff.w >> 16)),    b2f((unsigned short)(cc.w >> 16)),    sel);
      }
      sel += __shfl_xor(sel, 1, 64);
      sel += __shfl_xor(sel, 2, 64);
      sel += __shfl_xor(sel, 4, 64);
      if (sub == 0) {
        float fsq = fsqg[b * 16384 + p0 + p];
        float msq = (csqg[b * 80 + cid] - 2.f * sel + fsq) * (1.f / 256.f);
        alphal[p] = expf(-msq);
        cidl[p] = cid;
      }
    }

    f32x4 acc[2][4];
    f32x4 zz = {0.f, 0.f, 0.f, 0.f};
    #pragma unroll
    for (int ml = 0; ml < 2; ++ml)
      #pragma unroll
      for (int pt = 0; pt < 4; ++pt) acc[ml][pt] = zz;

    #pragma unroll
    for (int ks = 0; ks < 8; ++ks) {
      bf16x8 bfr[4];
      #pragma unroll
      for (int pt = 0; pt < 4; ++pt)
        bfr[pt] = *(const bf16x8*)&featT[cur][(pt * 16 + lo) * 264 + ks * 32 + hi * 8];
      #pragma unroll
      for (int ml = 0; ml < 2; ++ml)
        #pragma unroll
        for (int pt = 0; pt < 4; ++pt)
          acc[ml][pt] = __builtin_amdgcn_mfma_f32_16x16x32_bf16(wf[ml][ks], bfr[pt], acc[ml][pt], 0, 0, 0);
    }
    __syncthreads();   // alphal/cidl ready; featT[cur] reads done; nxv drained

    #pragma unroll
    for (int pt = 0; pt < 4; ++pt) {
      int plx = pt * 16 + lo;
      int p = p0 + plx;
      float a = alphal[plx];
      float om = 1.f - a;
      const float* crow = chatg + ((size_t)b * 80 + cidl[plx]) * 256;
      #pragma unroll
      for (int ml = 0; ml < 2; ++ml) {
        int o0 = w * 32 + ml * 16 + hi * 4;
        float4 c4 = *(const float4*)&crow[o0];
        size_t ob = ((size_t)b * 256 + o0) * 16384 + p;
        out[ob            ] = fmaxf(fmaf(a, c4.x, om * acc[ml][pt][0]) + bias2[ml][0], 0.f);
        out[ob + 16384    ] = fmaxf(fmaf(a, c4.y, om * acc[ml][pt][1]) + bias2[ml][1], 0.f);
        out[ob + 2 * 16384] = fmaxf(fmaf(a, c4.z, om * acc[ml][pt][2]) + bias2[ml][2], 0.f);
        out[ob + 3 * 16384] = fmaxf(fmaf(a, c4.w, om * acc[ml][pt][3]) + bias2[ml][3], 0.f);
      }
    }

    if (rep < 7) {
      #pragma unroll
      for (int jj = 0; jj < 4; ++jj) {
        union { unsigned short u[8]; uint4 q; } pk;
        #pragma unroll
        for (int e = 0; e < 8; ++e) pk.u[e] = f2b(nxv[jj * 8 + e]);
        *(uint4*)&featT[cur ^ 1][pl * 264 + cph * 32 + jj * 8] = pk.q;
      }
    }
  }
}

extern "C" void kernel_launch(void* const* d_in, const int* in_sizes, int n_in,
                              void* d_out, int out_size, void* d_ws, size_t ws_size,
                              hipStream_t stream) {
  (void)in_sizes; (void)n_in; (void)out_size; (void)ws_size;
  const float* feat = (const float*)d_in[0];
  const float* cent = (const float*)d_in[1];
  const float* fcw  = (const float*)d_in[2];
  const float* fcb  = (const float*)d_in[3];
  float* out = (float*)d_out;
  char* ws = (char*)d_ws;
  unsigned short* cnksh  = (unsigned short*)(ws);
  unsigned short* cnksl  = (unsigned short*)(ws + 40960);
  float* cnT             = (float*)(ws + 81920);
  float* wt              = (float*)(ws + 163840);
  unsigned short* wks    = (unsigned short*)(ws + 425984);
  unsigned short* centf  = (unsigned short*)(ws + 557056);
  u8*    idxb            = (u8*)(ws + 1212416);
  float* fsq             = (float*)(ws + 1474560);
  int*   cntg            = (int*)(ws + 2523136);
  float* csq             = (float*)(ws + 2528256);
  float* chat            = (float*)(ws + 2533376);
  float* part            = (float*)(ws + 3844096);

  k0_cnorm<<<80, 256, 0, stream>>>(cent, cnksh, cnksl, cnT, cntg);
  k0_wprep<<<256, 256, 0, stream>>>(fcw, wks, wt);
  k1f<<<1024, 256, 0, stream>>>(feat, cnksh, cnksl, cnT, idxb, fsq, cntg, part);
  k2_cent<<<1280, 256, 0, stream>>>(part, cntg, wt, centf, csq, chat);
  k3b_gemm<<<512, 512, 0, stream>>>(feat, idxb, fsq, csq, centf, chat, wks, fcb, out);
}

// Round 13
// 483.772 us; speedup vs baseline: 1.3689x; 1.0118x over previous
//
#include <hip/hip_runtime.h>

// Refine: out = relu((1-a)*(W f) + a*chat[idx] + bias)
// a = exp(-(csq - 2*<f,cent[idx]> + fsq)/256), chat = W*cent
// idx = argmax_n <f, cnorm_n> — bf16-MFMA screen from LDS + exact-f32 fallback on near-ties
//
// ws layout (1 GiB available; ~88 MB used):
//  cnkh [8][96][32] bf16  @ 0         (cnorm k-slices, rows 80-95 zero-padded)
//  cnT  [256][80] f32     @ 49152     (exact cnorm for fallback)
//  wt   [256][256] f32    @ 131072
//  wks  [8][256][32] bf16 @ 393216
//  centf[16][80][256] bf16 @ 524288
//  idxb [16*16384] u8     @ 1179648
//  fsq  [16*16384] f32    @ 1441792
//  cnt  [16*80] i32       @ 2490368   (zeroed by k0_cnorm)
//  csq  [16*80] f32       @ 2495488
//  chat [16][80][256] f32 @ 2500608
//  part [16][64][80][256] f32 @ 3811328 (per-block sumx partials, NON-atomic)

typedef __bf16 bf16x8 __attribute__((ext_vector_type(8)));
typedef float  f32x4  __attribute__((ext_vector_type(4)));
typedef unsigned char u8;

__device__ __forceinline__ unsigned short f2b(float f) {
  unsigned u = __float_as_uint(f);
  return (unsigned short)((u + 0x7fffu + ((u >> 16) & 1u)) >> 16);
}
__device__ __forceinline__ float b2f(unsigned short s) {
  return __uint_as_float((unsigned)s << 16);
}

// -- K0a: normalized centroids -> cnkh (96-pad) + f32 cnT + zero cntg ----------
__global__ __launch_bounds__(256) void k0_cnorm(const float* __restrict__ cent,
                                                unsigned short* __restrict__ cnkh,
                                                float* __restrict__ cnT,
                                                int* __restrict__ cntg) {
  int n = blockIdx.x, t = threadIdx.x;
  if (n >= 80) {                                   // pad rows: zeros
    cnkh[((t >> 5) * 96 + n) * 32 + (t & 31)] = 0;
    return;
  }
  if (t < 16) cntg[n * 16 + t] = 0;
  float v = cent[n * 256 + t];
  float s = v * v;
  #pragma unroll
  for (int o = 32; o > 0; o >>= 1) s += __shfl_down(s, o, 64);
  __shared__ float red[4];
  if ((t & 63) == 0) red[t >> 6] = s;
  __syncthreads();
  float tot = red[0] + red[1] + red[2] + red[3];
  float dn = fmaxf(sqrtf(tot), 1e-12f);
  float val = v / dn;
  cnT[t * 80 + n] = val;
  cnkh[((t >> 5) * 96 + n) * 32 + (t & 31)] = f2b(val);
}

// ---------------- K0b: W prep: bf16 k-sliced [k][o][32] + W^T f32 -------------
__global__ __launch_bounds__(256) void k0_wprep(const float* __restrict__ fcw,
                                                unsigned short* __restrict__ wks,
                                                float* __restrict__ wt) {
  int o = blockIdx.x, c = threadIdx.x;
  float w = fcw[o * 256 + c];
  wt[c * 256 + o] = w;
  wks[((c >> 5) * 256 + o) * 32 + (c & 31)] = f2b(w);
}

// ---- K1F: LDS-staged tiles: MFMA sim-screen + exact fallback + sumx ----------
__global__ __launch_bounds__(512) void k1f(const float* __restrict__ feat,
    const unsigned short* __restrict__ cnkh, const float* __restrict__ cnT,
    u8* __restrict__ idxb, float* __restrict__ fsqg, int* __restrict__ cntg,
    float* __restrict__ part) {
  __shared__ alignas(16) unsigned short featH[64 * 264];  // 33.8 KB
  __shared__ float simL[96 * 64];                         // 24.6 KB
  __shared__ float fsqL[64][8];
  __shared__ float pmaxv[8][64];
  __shared__ u8    pmaxi[8][64];
  __shared__ float bestvL[64];
  __shared__ unsigned cmaskL[64][3];
  __shared__ int   ccntL[64];
  __shared__ alignas(8) u8 idx64[64];
  __shared__ int   lh[80];

  const int b = blockIdx.x >> 6, chunk = blockIdx.x & 63;
  const int px0 = chunk << 8;
  const int t = threadIdx.x, wv = t >> 6, ln = t & 63, lo = ln & 15, hi = ln >> 4;
  const int pl = t & 63, cph = t >> 6;            // stager: pixel, 32-ch group
  const float DELTA = 2.5e-2f;

  if (t < 80) lh[t] = 0;

  f32x4 accS[5][2];
  f32x4 zz = {0.f, 0.f, 0.f, 0.f};
  #pragma unroll
  for (int mt = 0; mt < 5; ++mt) { accS[mt][0] = zz; accS[mt][1] = zz; }

  { // prologue: stage tile 0 (coalesced 256B/wave loads) + fsq partial
    const float* fb = feat + ((size_t)b * 256 + cph * 32) * 16384 + px0 + pl;
    float fs = 0.f;
    #pragma unroll
    for (int jj = 0; jj < 4; ++jj) {
      union { unsigned short u[8]; uint4 q; } pk;
      #pragma unroll
      for (int e = 0; e < 8; ++e) {
        float v = fb[(size_t)(jj * 8 + e) * 16384];
        fs = fmaf(v, v, fs);
        pk.u[e] = f2b(v);
      }
      *(uint4*)&featH[pl * 264 + cph * 32 + jj * 8] = pk.q;
    }
    fsqL[pl][cph] = fs;
  }

  for (int tile = 0; tile < 4; ++tile) {
    __syncthreads();                               // B1: featH/fsqL ready

    float nxv[32];
    if (tile < 3) {                                // prefetch next tile
      const float* fb2 = feat + ((size_t)b * 256 + cph * 32) * 16384 + px0 + (tile + 1) * 64 + pl;
      #pragma unroll
      for (int e = 0; e < 32; ++e) nxv[e] = fb2[(size_t)e * 16384];
    }

    { // SIM: 24 (m,nt) pairs over 8 waves, 3 each; b128 LDS reads (k3b pattern)
      f32x4 a3[3] = {zz, zz, zz};
      for (int ks = 0; ks < 8; ++ks) {
        bf16x8 bfr[3], ca[3];
        #pragma unroll
        for (int i = 0; i < 3; ++i) {
          int pr = wv * 3 + i; int m = pr >> 2, nt = pr & 3;
          bfr[i] = *(const bf16x8*)&featH[(nt * 16 + lo) * 264 + ks * 32 + hi * 8];
          ca[i]  = *(const bf16x8*)&cnkh[((size_t)ks * 96 + m * 16 + lo) * 32 + hi * 8];
        }
        #pragma unroll
        for (int i = 0; i < 3; ++i)
          a3[i] = __builtin_amdgcn_mfma_f32_16x16x32_bf16(ca[i], bfr[i], a3[i], 0, 0, 0);
      }
      #pragma unroll
      for (int i = 0; i < 3; ++i) {
        int pr = wv * 3 + i; int m = pr >> 2, nt = pr & 3;
        #pragma unroll
        for (int r = 0; r < 4; ++r)
          simL[(m * 16 + hi * 4 + r) * 64 + nt * 16 + lo] = a3[i][r];
      }
    }
    __syncthreads();                               // B2: simL ready

    { // PASS1: 8 ranges x 10 classes, per-px partial max (first-index ties)
      int base = cph * 10;
      float mv = simL[base * 64 + pl]; int mi = base;
      #pragma unroll
      for (int i = 1; i < 10; ++i) {
        float v = simL[(base + i) * 64 + pl];
        if (v > mv) { mv = v; mi = base + i; }
      }
      pmaxv[cph][pl] = mv; pmaxi[cph][pl] = (u8)mi;
    }
    __syncthreads();                               // B3

    if (t < 64) {                                  // FINAL reduce + init masks + fsq
      float bv = pmaxv[0][t]; int bi = pmaxi[0][t];
      #pragma unroll
      for (int r = 1; r < 8; ++r) {
        float v = pmaxv[r][t];
        if (v > bv) { bv = v; bi = pmaxi[r][t]; }
      }
      bestvL[t] = bv; idx64[t] = (u8)bi;
      ccntL[t] = 0; cmaskL[t][0] = 0; cmaskL[t][1] = 0; cmaskL[t][2] = 0;
      float fs = 0.f;
      #pragma unroll
      for (int g = 0; g < 8; ++g) fs += fsqL[t][g];
      fsqg[b * 16384 + px0 + tile * 64 + t] = fs;
    }
    __syncthreads();                               // B4

    { // PASS2: flag candidates within DELTA of best
      int base = cph * 10;
      float thr = bestvL[pl] - DELTA;
      int c = 0; unsigned mrg[3] = {0, 0, 0};
      #pragma unroll
      for (int i = 0; i < 10; ++i) {
        if (simL[(base + i) * 64 + pl] >= thr) {
          int cls = base + i; ++c; mrg[cls >> 5] |= 1u << (cls & 31);
        }
      }
      if (c) {
        atomicAdd(&ccntL[pl], c);
        if (mrg[0]) atomicOr(&cmaskL[pl][0], mrg[0]);
        if (mrg[1]) atomicOr(&cmaskL[pl][1], mrg[1]);
        if (mrg[2]) atomicOr(&cmaskL[pl][2], mrg[2]);
      }
    }
    __syncthreads();                               // B5

    // FALLBACK: one wave per flagged px; exact f32 dot over L2-hot feat/cnT
    for (int px = wv; px < 64; px += 8) {
      if (ccntL[px] <= 1) continue;
      const float* fp = feat + ((size_t)b * 256 + ln) * 16384 + px0 + tile * 64 + px;
      float fv0 = fp[0];
      float fv1 = fp[(size_t)64 * 16384];
      float fv2 = fp[(size_t)128 * 16384];
      float fv3 = fp[(size_t)192 * 16384];
      float bd = -3.4e38f; int bc = 255;
      for (int w3 = 0; w3 < 3; ++w3) {
        unsigned m = cmaskL[px][w3];
        while (m) {
          int s = __ffs(m) - 1; m &= m - 1;
          int cls = w3 * 32 + s;
          float d = fv0 * cnT[ln * 80 + cls];
          d = fmaf(fv1, cnT[(ln + 64) * 80 + cls], d);
          d = fmaf(fv2, cnT[(ln + 128) * 80 + cls], d);
          d = fmaf(fv3, cnT[(ln + 192) * 80 + cls], d);
          #pragma unroll
          for (int off = 1; off <= 32; off <<= 1) d += __shfl_xor(d, off, 64);
          if (d > bd) { bd = d; bc = cls; }        // ascending cls -> first-max
        }
      }
      if (ln == 0) idx64[px] = (u8)bc;
    }
    __syncthreads();                               // B6: idx64 final

    if (t < 64) {                                  // idx out + histogram
      int id = idx64[t];
      idxb[b * 16384 + px0 + tile * 64 + t] = (u8)id;
      atomicAdd(&lh[id], 1);
    }

    { // SUMX: one-hot MFMA from LDS; wave owns 32 channels (2 n-tiles)
      #pragma unroll
      for (int ks = 0; ks < 2; ++ks) {
        uint2 iv = *(const uint2*)&idx64[ks * 32 + hi * 8];
        int id[8];
        #pragma unroll
        for (int j = 0; j < 4; ++j) { id[j] = (iv.x >> (8 * j)) & 255; id[4 + j] = (iv.y >> (8 * j)) & 255; }
        union { unsigned short u[8]; bf16x8 v; } ma[5];
        #pragma unroll
        for (int mt = 0; mt < 5; ++mt) {
          int row = mt * 16 + lo;
          #pragma unroll
          for (int j = 0; j < 8; ++j) ma[mt].u[j] = (id[j] == row) ? (unsigned short)0x3F80 : (unsigned short)0;
        }
        #pragma unroll
        for (int nt = 0; nt < 2; ++nt) {
          union { unsigned short u[8]; bf16x8 v; } bb;
          #pragma unroll
          for (int j = 0; j < 8; ++j)
            bb.u[j] = featH[(ks * 32 + hi * 8 + j) * 264 + wv * 32 + nt * 16 + lo];
          #pragma unroll
          for (int mt = 0; mt < 5; ++mt)
            accS[mt][nt] = __builtin_amdgcn_mfma_f32_16x16x32_bf16(ma[mt].v, bb.v, accS[mt][nt], 0, 0, 0);
        }
      }
    }
    __syncthreads();                               // B7: featH reads done

    if (tile < 3) {                                // write prefetched tile + fsq
      float fs = 0.f;
      #pragma unroll
      for (int jj = 0; jj < 4; ++jj) {
        union { unsigned short u[8]; uint4 q; } pk;
        #pragma unroll
        for (int e = 0; e < 8; ++e) {
          float v = nxv[jj * 8 + e];
          fs = fmaf(v, v, fs);
          pk.u[e] = f2b(v);
        }
        *(uint4*)&featH[pl * 264 + cph * 32 + jj * 8] = pk.q;
      }
      fsqL[pl][cph] = fs;
    }
  }
  __syncthreads();
  if (t < 80) atomicAdd(&cntg[b * 80 + t], lh[t]);
  float* pb = part + (size_t)(b * 64 + chunk) * 80 * 256;
  #pragma unroll
  for (int mt = 0; mt < 5; ++mt)
    #pragma unroll
    for (int nt = 0; nt < 2; ++nt)
      #pragma unroll
      for (int r = 0; r < 4; ++r)
        pb[(mt * 16 + hi * 4 + r) * 256 + wv * 32 + nt * 16 + lo] = accS[mt][nt][r];
}

// -------- K2: cent = Σ64 partials / max(cnt,1); csq; centf; chat = W*cent -----
__global__ __launch_bounds__(256) void k2_cent(const float* __restrict__ part,
                                               const int* __restrict__ cntg,
                                               const float* __restrict__ wt,
                                               unsigned short* __restrict__ centf,
                                               float* __restrict__ csqg,
                                               float* __restrict__ chatg) {
  int bn = blockIdx.x; int b = bn / 80, n = bn - b * 80; int t = threadIdx.x;
  float dn = fmaxf((float)cntg[bn], 1.0f);
  float s = 0.f;
  const float* pp = part + ((size_t)(b * 64) * 80 + n) * 256 + t;
  #pragma unroll 8
  for (int ck = 0; ck < 64; ++ck) s += pp[(size_t)ck * 80 * 256];
  float cv = s / dn;
  __shared__ float cl[256];
  __shared__ float red[4];
  cl[t] = cv;
  centf[(size_t)bn * 256 + t] = f2b(cv);
  float q = cv * cv;
  #pragma unroll
  for (int o = 32; o > 0; o >>= 1) q += __shfl_down(q, o, 64);
  if ((t & 63) == 0) red[t >> 6] = q;
  __syncthreads();
  if (t == 0) csqg[bn] = red[0] + red[1] + red[2] + red[3];
  float acc = 0.f;
  #pragma unroll 4
  for (int c = 0; c < 256; ++c) acc = fmaf(wt[c * 256 + t], cl[c], acc);
  chatg[(size_t)bn * 256 + t] = acc;
}

// ---------------- K3b: pipelined W-in-registers MFMA GEMM + alpha + epilogue --
__global__ __launch_bounds__(512) void k3b_gemm(const float* __restrict__ feat,
    const u8* __restrict__ idxb, const float* __restrict__ fsqg,
    const float* __restrict__ csqg, const unsigned short* __restrict__ centf,
    const float* __restrict__ chatg, const unsigned short* __restrict__ wks,
    const float* __restrict__ fcb, float* __restrict__ out) {
  __shared__ alignas(16) unsigned short featT[2][64 * 264];  // double-buffered
  __shared__ float alphal[64];
  __shared__ int cidl[64];
  const int t = threadIdx.x;
  const int w = t >> 6, ln = t & 63, lo = ln & 15, hi = ln >> 4;
  const int pl = ln, cph = w;

  bf16x8 wf[2][8];
  #pragma unroll
  for (int ml = 0; ml < 2; ++ml)
    #pragma unroll
    for (int ks = 0; ks < 8; ++ks)
      wf[ml][ks] = *(const bf16x8*)&wks[((size_t)ks * 256 + (w * 2 + ml) * 16 + lo) * 32 + hi * 8];
  f32x4 bias2[2];
  #pragma unroll
  for (int ml = 0; ml < 2; ++ml)
    bias2[ml] = *(const f32x4*)&fcb[w * 32 + ml * 16 + hi * 4];

  const int tile0 = blockIdx.x * 8;
  {
    int b = tile0 >> 8, p0 = (tile0 & 255) << 6;
    const float* fb = feat + ((size_t)b * 256 + cph * 32) * 16384 + p0 + pl;
    #pragma unroll
    for (int jj = 0; jj < 4; ++jj) {
      union { unsigned short u[8]; uint4 q; } pk;
      #pragma unroll
      for (int e = 0; e < 8; ++e) pk.u[e] = f2b(fb[(size_t)(jj * 8 + e) * 16384]);
      *(uint4*)&featT[0][pl * 264 + cph * 32 + jj * 8] = pk.q;
    }
  }

  float nxv[32];
  for (int rep = 0; rep < 8; ++rep) {
    const int cur = rep & 1;
    const int tile = tile0 + rep;
    const int b = tile >> 8, p0 = (tile & 255) << 6;

    __syncthreads();

    if (rep < 7) {
      int t2 = tile + 1;
      int b2 = t2 >> 8, p02 = (t2 & 255) << 6;
      const float* fb2 = feat + ((size_t)b2 * 256 + cph * 32) * 16384 + p02 + pl;
      #pragma unroll
      for (int e = 0; e < 32; ++e) nxv[e] = fb2[(size_t)e * 16384];
    }

    {
      int p = t >> 3, sub = t & 7;
      int cid = idxb[b * 16384 + p0 + p];
      const unsigned short* cw = centf + ((size_t)b * 80 + cid) * 256 + sub * 32;
      const unsigned short* fr = &featT[cur][p * 264 + sub * 32];
      float sel = 0.f;
      #pragma unroll
      for (int j = 0; j < 4; ++j) {
        uint4 cc = *(const uint4*)&cw[j * 8];
        uint4 ff = *(const uint4*)&fr[j * 8];
        sel = fmaf(b2f((unsigned short)(ff.x & 0xffff)), b2f((unsigned short)(cc.x & 0xffff)), sel);
        sel = fmaf(b2f((unsigned short)(ff.x >> 16)),    b2f((unsigned short)(cc.x >> 16)),    sel);
        sel = fmaf(b2f((unsigned short)(ff.y & 0xffff)), b2f((unsigned short)(cc.y & 0xffff)), sel);
        sel = fmaf(b2f((unsigned short)(ff.y >> 16)),    b2f((unsigned short)(cc.y >> 16)),    sel);
        sel = fmaf(b2f((unsigned short)(ff.z & 0xffff)), b2f((unsigned short)(cc.z & 0xffff)), sel);
        sel = fmaf(b2f((unsigned short)(ff.z >> 16)),    b2f((unsigned short)(cc.z >> 16)),    sel);
        sel = fmaf(b2f((unsigned short)(ff.w & 0xffff)), b2f((unsigned short)(cc.w & 0xffff)), sel);
        sel = fmaf(b2f((unsigned short)(ff.w >> 16)),    b2f((unsigned short)(cc.w >> 16)),    sel);
      }
      sel += __shfl_xor(sel, 1, 64);
      sel += __shfl_xor(sel, 2, 64);
      sel += __shfl_xor(sel, 4, 64);
      if (sub == 0) {
        float fsq = fsqg[b * 16384 + p0 + p];
        float msq = (csqg[b * 80 + cid] - 2.f * sel + fsq) * (1.f / 256.f);
        alphal[p] = expf(-msq);
        cidl[p] = cid;
      }
    }

    f32x4 acc[2][4];
    f32x4 zz = {0.f, 0.f, 0.f, 0.f};
    #pragma unroll
    for (int ml = 0; ml < 2; ++ml)
      #pragma unroll
      for (int pt = 0; pt < 4; ++pt) acc[ml][pt] = zz;

    #pragma unroll
    for (int ks = 0; ks < 8; ++ks) {
      bf16x8 bfr[4];
      #pragma unroll
      for (int pt = 0; pt < 4; ++pt)
        bfr[pt] = *(const bf16x8*)&featT[cur][(pt * 16 + lo) * 264 + ks * 32 + hi * 8];
      #pragma unroll
      for (int ml = 0; ml < 2; ++ml)
        #pragma unroll
        for (int pt = 0; pt < 4; ++pt)
          acc[ml][pt] = __builtin_amdgcn_mfma_f32_16x16x32_bf16(wf[ml][ks], bfr[pt], acc[ml][pt], 0, 0, 0);
    }
    __syncthreads();

    #pragma unroll
    for (int pt = 0; pt < 4; ++pt) {
      int plx = pt * 16 + lo;
      int p = p0 + plx;
      float a = alphal[plx];
      float om = 1.f - a;
      const float* crow = chatg + ((size_t)b * 80 + cidl[plx]) * 256;
      #pragma unroll
      for (int ml = 0; ml < 2; ++ml) {
        int o0 = w * 32 + ml * 16 + hi * 4;
        float4 c4 = *(const float4*)&crow[o0];
        size_t ob = ((size_t)b * 256 + o0) * 16384 + p;
        out[ob            ] = fmaxf(fmaf(a, c4.x, om * acc[ml][pt][0]) + bias2[ml][0], 0.f);
        out[ob + 16384    ] = fmaxf(fmaf(a, c4.y, om * acc[ml][pt][1]) + bias2[ml][1], 0.f);
        out[ob + 2 * 16384] = fmaxf(fmaf(a, c4.z, om * acc[ml][pt][2]) + bias2[ml][2], 0.f);
        out[ob + 3 * 16384] = fmaxf(fmaf(a, c4.w, om * acc[ml][pt][3]) + bias2[ml][3], 0.f);
      }
    }

    if (rep < 7) {
      #pragma unroll
      for (int jj = 0; jj < 4; ++jj) {
        union { unsigned short u[8]; uint4 q; } pk;
        #pragma unroll
        for (int e = 0; e < 8; ++e) pk.u[e] = f2b(nxv[jj * 8 + e]);
        *(uint4*)&featT[cur ^ 1][pl * 264 + cph * 32 + jj * 8] = pk.q;
      }
    }
  }
}

extern "C" void kernel_launch(void* const* d_in, const int* in_sizes, int n_in,
                              void* d_out, int out_size, void* d_ws, size_t ws_size,
                              hipStream_t stream) {
  (void)in_sizes; (void)n_in; (void)out_size; (void)ws_size;
  const float* feat = (const float*)d_in[0];
  const float* cent = (const float*)d_in[1];
  const float* fcw  = (const float*)d_in[2];
  const float* fcb  = (const float*)d_in[3];
  float* out = (float*)d_out;
  char* ws = (char*)d_ws;
  unsigned short* cnkh   = (unsigned short*)(ws);
  float* cnT             = (float*)(ws + 49152);
  float* wt              = (float*)(ws + 131072);
  unsigned short* wks    = (unsigned short*)(ws + 393216);
  unsigned short* centf  = (unsigned short*)(ws + 524288);
  u8*    idxb            = (u8*)(ws + 1179648);
  float* fsq             = (float*)(ws + 1441792);
  int*   cntg            = (int*)(ws + 2490368);
  float* csq             = (float*)(ws + 2495488);
  float* chat            = (float*)(ws + 2500608);
  float* part            = (float*)(ws + 3811328);

  k0_cnorm<<<96, 256, 0, stream>>>(cent, cnkh, cnT, cntg);
  k0_wprep<<<256, 256, 0, stream>>>(fcw, wks, wt);
  k1f<<<1024, 512, 0, stream>>>(feat, cnkh, cnT, idxb, fsq, cntg, part);
  k2_cent<<<1280, 256, 0, stream>>>(part, cntg, wt, centf, csq, chat);
  k3b_gemm<<<512, 512, 0, stream>>>(feat, idxb, fsq, csq, centf, chat, wks, fcb, out);
}

// Round 14
// 454.750 us; speedup vs baseline: 1.4563x; 1.0638x over previous
//
#include <hip/hip_runtime.h>

// Refine: out = relu((1-a)*(W f) + a*chat[idx] + bias)
// a = exp(-(csq - 2*<f,cent[idx]> + fsq)/256), chat = W*cent
// idx = argmax_n <f, cnorm_n>
//
// ws layout (6.38 MB):
//  cnT    [256][80] f32        @ 0
//  wt     [256][256] f32       @ 81920
//  wks    [8][256][32] bf16    @ 344064
//  centf  [16][80][256] bf16   @ 475136
//  idxb   [16*16384] u8        @ 1130496
//  fsq    [16*16384] f32       @ 1392640
//  cnt    [16*80] i32          @ 2441216  (zeroed by k0_cnorm)
//  csq    [16*80] f32          @ 2446336
//  chat   [16][80][256] f32    @ 2451456
//  sumxp  [4][16][80][256] bf16 @ 3762176  (split-K partials, non-atomic)

typedef __bf16 bf16x8 __attribute__((ext_vector_type(8)));
typedef float  f32x4  __attribute__((ext_vector_type(4)));
typedef unsigned char u8;

__device__ __forceinline__ unsigned short f2b(float f) {
  unsigned u = __float_as_uint(f);
  return (unsigned short)((u + 0x7fffu + ((u >> 16) & 1u)) >> 16);
}
__device__ __forceinline__ float b2f(unsigned short s) {
  return __uint_as_float((unsigned)s << 16);
}

// ---------------- K0a: normalized centroids [c][n] + zero cntg ----------------
__global__ __launch_bounds__(256) void k0_cnorm(const float* __restrict__ cent,
                                                float* __restrict__ cnT,
                                                int* __restrict__ cntg) {
  int n = blockIdx.x, t = threadIdx.x;
  if (t < 16) cntg[n * 16 + t] = 0;
  float v = cent[n * 256 + t];
  float s = v * v;
  #pragma unroll
  for (int o = 32; o > 0; o >>= 1) s += __shfl_down(s, o, 64);
  __shared__ float red[4];
  if ((t & 63) == 0) red[t >> 6] = s;
  __syncthreads();
  float tot = red[0] + red[1] + red[2] + red[3];
  float dn = fmaxf(sqrtf(tot), 1e-12f);
  cnT[t * 80 + n] = v / dn;
}

// ---------------- K0b: W prep: bf16 k-sliced [k][o][32] + W^T f32 -------------
__global__ __launch_bounds__(256) void k0_wprep(const float* __restrict__ fcw,
                                                unsigned short* __restrict__ wks,
                                                float* __restrict__ wt) {
  int o = blockIdx.x, c = threadIdx.x;
  float w = fcw[o * 256 + c];
  wt[c * 256 + o] = w;
  wks[((c >> 5) * 256 + o) * 32 + (c & 31)] = f2b(w);
}

// ------- K1: per-pixel argmax over 80 dots (f32) + fsq + counts ---------------
// __launch_bounds__(256, 2): VGPR cap 256 -> g[80] stays in registers (no spill)
__global__ __launch_bounds__(256, 2) void k1_argmax(const float* __restrict__ feat,
                                                    const float* __restrict__ cnT,
                                                    u8* __restrict__ idxb,
                                                    float* __restrict__ fsqg,
                                                    int* __restrict__ cntg) {
  __shared__ int lh[80];
  int t = threadIdx.x;
  if (t < 80) lh[t] = 0;
  __syncthreads();
  int b = blockIdx.x >> 6;
  int pi = ((blockIdx.x & 63) << 8) | t;
  const float* fb = feat + (size_t)b * 256 * 16384 + pi;
  float g[80];
  #pragma unroll
  for (int n = 0; n < 80; ++n) g[n] = 0.f;
  float fsq = 0.f;
  #pragma unroll 4
  for (int c = 0; c < 256; ++c) {
    float v = fb[(size_t)c * 16384];
    fsq = fmaf(v, v, fsq);
    const float* cr = cnT + c * 80;
    #pragma unroll
    for (int n = 0; n < 80; ++n) g[n] = fmaf(v, cr[n], g[n]);
  }
  float best = g[0]; int bi = 0;
  #pragma unroll
  for (int n = 1; n < 80; ++n) if (g[n] > best) { best = g[n]; bi = n; }
  idxb[b * 16384 + pi] = (u8)bi;
  fsqg[b * 16384 + pi] = fsq;
  atomicAdd(&lh[bi], 1);
  __syncthreads();
  if (t < 80) atomicAdd(&cntg[b * 80 + t], lh[t]);
}

// ---------------- K1b: sumx = onehot(idx) * feat^T via MFMA (split-K=4) -------
__global__ __launch_bounds__(256) void k1b_gemm(const float* __restrict__ feat,
                                                const u8* __restrict__ idxb,
                                                unsigned short* __restrict__ sumxp) {
  int bid = blockIdx.x;
  int kp = bid & 3, ns = (bid >> 2) & 7, b = bid >> 5;
  int t = threadIdx.x, wv = t >> 6, ln = t & 63, lo = ln & 15, hi = ln >> 4;
  int nt = wv & 1;
  int m0 = (wv >> 1) ? 3 : 0, nm = (wv >> 1) ? 2 : 3;
  int c = ns * 32 + nt * 16 + lo;
  const float* fp = feat + (((size_t)b * 256 + c) * 16384 + kp * 4096 + hi * 8);
  const u8* ip = idxb + b * 16384 + kp * 4096 + hi * 8;
  f32x4 acc[3];
  f32x4 zz = {0.f, 0.f, 0.f, 0.f};
  acc[0] = zz; acc[1] = zz; acc[2] = zz;
  for (int ks = 0; ks < 128; ++ks) {
    float4 v0 = *(const float4*)(fp + ks * 32);
    float4 v1 = *(const float4*)(fp + ks * 32 + 4);
    union { unsigned short u[8]; bf16x8 v; } bb;
    bb.u[0] = f2b(v0.x); bb.u[1] = f2b(v0.y); bb.u[2] = f2b(v0.z); bb.u[3] = f2b(v0.w);
    bb.u[4] = f2b(v1.x); bb.u[5] = f2b(v1.y); bb.u[6] = f2b(v1.z); bb.u[7] = f2b(v1.w);
    uint2 iv = *(const uint2*)(ip + ks * 32);
    int id[8];
    #pragma unroll
    for (int j = 0; j < 4; ++j) { id[j] = (iv.x >> (8 * j)) & 255; id[4 + j] = (iv.y >> (8 * j)) & 255; }
    #pragma unroll
    for (int mi = 0; mi < 3; ++mi) {
      if (mi >= nm) break;
      int row = (m0 + mi) * 16 + lo;
      union { unsigned short u[8]; bf16x8 v; } ma;
      #pragma unroll
      for (int j = 0; j < 8; ++j) ma.u[j] = (id[j] == row) ? (unsigned short)0x3F80 : (unsigned short)0;
      acc[mi] = __builtin_amdgcn_mfma_f32_16x16x32_bf16(ma.v, bb.v, acc[mi], 0, 0, 0);
    }
  }
  #pragma unroll
  for (int mi = 0; mi < 3; ++mi) {
    if (mi >= nm) break;
    #pragma unroll
    for (int r = 0; r < 4; ++r) {
      int cls = (m0 + mi) * 16 + hi * 4 + r;
      sumxp[(((size_t)kp * 16 + b) * 80 + cls) * 256 + ns * 32 + nt * 16 + lo] = f2b(acc[mi][r]);
    }
  }
}

// ---------------- K2: cent = sum/max(cnt,1); csq; centf bf16; chat = W*cent ---
__global__ __launch_bounds__(256) void k2_cent(const unsigned short* __restrict__ sumxp,
                                               const int* __restrict__ cntg,
                                               const float* __restrict__ wt,
                                               unsigned short* __restrict__ centf,
                                               float* __restrict__ csqg,
                                               float* __restrict__ chatg) {
  int bn = blockIdx.x; int t = threadIdx.x;
  float dn = fmaxf((float)cntg[bn], 1.0f);
  float s = 0.f;
  #pragma unroll
  for (int kp = 0; kp < 4; ++kp)
    s += b2f(sumxp[((size_t)kp * 1280 + bn) * 256 + t]);   // [kp][b][n][c]
  float cv = s / dn;
  __shared__ float cl[256];
  __shared__ float red[4];
  cl[t] = cv;
  centf[(size_t)bn * 256 + t] = f2b(cv);
  float q = cv * cv;
  #pragma unroll
  for (int o = 32; o > 0; o >>= 1) q += __shfl_down(q, o, 64);
  if ((t & 63) == 0) red[t >> 6] = q;
  __syncthreads();
  if (t == 0) csqg[bn] = red[0] + red[1] + red[2] + red[3];
  float acc = 0.f;
  #pragma unroll 4
  for (int c = 0; c < 256; ++c) acc = fmaf(wt[c * 256 + t], cl[c], acc);
  chatg[(size_t)bn * 256 + t] = acc;
}

// ---------------- K3b: pipelined W-in-registers MFMA GEMM + alpha + epilogue --
__global__ __launch_bounds__(512) void k3b_gemm(const float* __restrict__ feat,
    const u8* __restrict__ idxb, const float* __restrict__ fsqg,
    const float* __restrict__ csqg, const unsigned short* __restrict__ centf,
    const float* __restrict__ chatg, const unsigned short* __restrict__ wks,
    const float* __restrict__ fcb, float* __restrict__ out) {
  __shared__ alignas(16) unsigned short featT[2][64 * 264];  // double-buffered
  __shared__ float alphal[64];
  __shared__ int cidl[64];
  const int t = threadIdx.x;
  const int w = t >> 6, ln = t & 63, lo = ln & 15, hi = ln >> 4;
  const int pl = ln, cph = w;

  bf16x8 wf[2][8];
  #pragma unroll
  for (int ml = 0; ml < 2; ++ml)
    #pragma unroll
    for (int ks = 0; ks < 8; ++ks)
      wf[ml][ks] = *(const bf16x8*)&wks[((size_t)ks * 256 + (w * 2 + ml) * 16 + lo) * 32 + hi * 8];
  f32x4 bias2[2];
  #pragma unroll
  for (int ml = 0; ml < 2; ++ml)
    bias2[ml] = *(const f32x4*)&fcb[w * 32 + ml * 16 + hi * 4];

  const int tile0 = blockIdx.x * 8;
  {
    int b = tile0 >> 8, p0 = (tile0 & 255) << 6;
    const float* fb = feat + ((size_t)b * 256 + cph * 32) * 16384 + p0 + pl;
    #pragma unroll
    for (int jj = 0; jj < 4; ++jj) {
      union { unsigned short u[8]; uint4 q; } pk;
      #pragma unroll
      for (int e = 0; e < 8; ++e) pk.u[e] = f2b(fb[(size_t)(jj * 8 + e) * 16384]);
      *(uint4*)&featT[0][pl * 264 + cph * 32 + jj * 8] = pk.q;
    }
  }

  float nxv[32];
  for (int rep = 0; rep < 8; ++rep) {
    const int cur = rep & 1;
    const int tile = tile0 + rep;
    const int b = tile >> 8, p0 = (tile & 255) << 6;

    __syncthreads();

    if (rep < 7) {
      int t2 = tile + 1;
      int b2 = t2 >> 8, p02 = (t2 & 255) << 6;
      const float* fb2 = feat + ((size_t)b2 * 256 + cph * 32) * 16384 + p02 + pl;
      #pragma unroll
      for (int e = 0; e < 32; ++e) nxv[e] = fb2[(size_t)e * 16384];
    }

    {
      int p = t >> 3, sub = t & 7;
      int cid = idxb[b * 16384 + p0 + p];
      const unsigned short* cw = centf + ((size_t)b * 80 + cid) * 256 + sub * 32;
      const unsigned short* fr = &featT[cur][p * 264 + sub * 32];
      float sel = 0.f;
      #pragma unroll
      for (int j = 0; j < 4; ++j) {
        uint4 cc = *(const uint4*)&cw[j * 8];
        uint4 ff = *(const uint4*)&fr[j * 8];
        sel = fmaf(b2f((unsigned short)(ff.x & 0xffff)), b2f((unsigned short)(cc.x & 0xffff)), sel);
        sel = fmaf(b2f((unsigned short)(ff.x >> 16)),    b2f((unsigned short)(cc.x >> 16)),    sel);
        sel = fmaf(b2f((unsigned short)(ff.y & 0xffff)), b2f((unsigned short)(cc.y & 0xffff)), sel);
        sel = fmaf(b2f((unsigned short)(ff.y >> 16)),    b2f((unsigned short)(cc.y >> 16)),    sel);
        sel = fmaf(b2f((unsigned short)(ff.z & 0xffff)), b2f((unsigned short)(cc.z & 0xffff)), sel);
        sel = fmaf(b2f((unsigned short)(ff.z >> 16)),    b2f((unsigned short)(cc.z >> 16)),    sel);
        sel = fmaf(b2f((unsigned short)(ff.w & 0xffff)), b2f((unsigned short)(cc.w & 0xffff)), sel);
        sel = fmaf(b2f((unsigned short)(ff.w >> 16)),    b2f((unsigned short)(cc.w >> 16)),    sel);
      }
      sel += __shfl_xor(sel, 1, 64);
      sel += __shfl_xor(sel, 2, 64);
      sel += __shfl_xor(sel, 4, 64);
      if (sub == 0) {
        float fsq = fsqg[b * 16384 + p0 + p];
        float msq = (csqg[b * 80 + cid] - 2.f * sel + fsq) * (1.f / 256.f);
        alphal[p] = expf(-msq);
        cidl[p] = cid;
      }
    }

    f32x4 acc[2][4];
    f32x4 zz = {0.f, 0.f, 0.f, 0.f};
    #pragma unroll
    for (int ml = 0; ml < 2; ++ml)
      #pragma unroll
      for (int pt = 0; pt < 4; ++pt) acc[ml][pt] = zz;

    #pragma unroll
    for (int ks = 0; ks < 8; ++ks) {
      bf16x8 bfr[4];
      #pragma unroll
      for (int pt = 0; pt < 4; ++pt)
        bfr[pt] = *(const bf16x8*)&featT[cur][(pt * 16 + lo) * 264 + ks * 32 + hi * 8];
      #pragma unroll
      for (int ml = 0; ml < 2; ++ml)
        #pragma unroll
        for (int pt = 0; pt < 4; ++pt)
          acc[ml][pt] = __builtin_amdgcn_mfma_f32_16x16x32_bf16(wf[ml][ks], bfr[pt], acc[ml][pt], 0, 0, 0);
    }
    __syncthreads();

    #pragma unroll
    for (int pt = 0; pt < 4; ++pt) {
      int plx = pt * 16 + lo;
      int p = p0 + plx;
      float a = alphal[plx];
      float om = 1.f - a;
      const float* crow = chatg + ((size_t)b * 80 + cidl[plx]) * 256;
      #pragma unroll
      for (int ml = 0; ml < 2; ++ml) {
        int o0 = w * 32 + ml * 16 + hi * 4;
        float4 c4 = *(const float4*)&crow[o0];
        size_t ob = ((size_t)b * 256 + o0) * 16384 + p;
        out[ob            ] = fmaxf(fmaf(a, c4.x, om * acc[ml][pt][0]) + bias2[ml][0], 0.f);
        out[ob + 16384    ] = fmaxf(fmaf(a, c4.y, om * acc[ml][pt][1]) + bias2[ml][1], 0.f);
        out[ob + 2 * 16384] = fmaxf(fmaf(a, c4.z, om * acc[ml][pt][2]) + bias2[ml][2], 0.f);
        out[ob + 3 * 16384] = fmaxf(fmaf(a, c4.w, om * acc[ml][pt][3]) + bias2[ml][3], 0.f);
      }
    }

    if (rep < 7) {
      #pragma unroll
      for (int jj = 0; jj < 4; ++jj) {
        union { unsigned short u[8]; uint4 q; } pk;
        #pragma unroll
        for (int e = 0; e < 8; ++e) pk.u[e] = f2b(nxv[jj * 8 + e]);
        *(uint4*)&featT[cur ^ 1][pl * 264 + cph * 32 + jj * 8] = pk.q;
      }
    }
  }
}

extern "C" void kernel_launch(void* const* d_in, const int* in_sizes, int n_in,
                              void* d_out, int out_size, void* d_ws, size_t ws_size,
                              hipStream_t stream) {
  (void)in_sizes; (void)n_in; (void)out_size; (void)ws_size;
  const float* feat = (const float*)d_in[0];
  const float* cent = (const float*)d_in[1];
  const float* fcw  = (const float*)d_in[2];
  const float* fcb  = (const float*)d_in[3];
  float* out = (float*)d_out;
  char* ws = (char*)d_ws;
  float* cnT             = (float*)(ws);
  float* wt              = (float*)(ws + 81920);
  unsigned short* wks    = (unsigned short*)(ws + 344064);
  unsigned short* centf  = (unsigned short*)(ws + 475136);
  u8*    idxb            = (u8*)(ws + 1130496);
  float* fsq             = (float*)(ws + 1392640);
  int*   cntg            = (int*)(ws + 2441216);
  float* csq             = (float*)(ws + 2446336);
  float* chat            = (float*)(ws + 2451456);
  unsigned short* sumxp  = (unsigned short*)(ws + 3762176);

  k0_cnorm<<<80, 256, 0, stream>>>(cent, cnT, cntg);
  k0_wprep<<<256, 256, 0, stream>>>(fcw, wks, wt);
  k1_argmax<<<1024, 256, 0, stream>>>(feat, cnT, idxb, fsq, cntg);
  k1b_gemm<<<512, 256, 0, stream>>>(feat, idxb, sumxp);
  k2_cent<<<1280, 256, 0, stream>>>(sumxp, cntg, wt, centf, csq, chat);
  k3b_gemm<<<512, 512, 0, stream>>>(feat, idxb, fsq, csq, centf, chat, wks, fcb, out);
}

// Round 15
// 429.522 us; speedup vs baseline: 1.5418x; 1.0587x over previous
//
#include <hip/hip_runtime.h>

// Refine: out = relu((1-a)*(W f) + a*chat[idx] + bias)
// a = exp(-(csq - 2*<f,cent[idx]> + fsq)/256), chat = W*cent
// idx = argmax_n <f, cnorm_n>
//
// ws layout (1 GiB available; ~88 MB used):
//  cnT    [256][80] f32        @ 0
//  wt     [256][256] f32       @ 81920
//  wks    [8][256][32] bf16    @ 344064
//  centf  [16][80][256] bf16   @ 475136
//  idxb   [16*16384] u8        @ 1130496
//  fsq    [16*16384] f32       @ 1392640
//  cnt    [16*80] i32          @ 2441216  (zeroed by k0_cnorm)
//  csq    [16*80] f32          @ 2446336
//  chat   [16][80][256] f32    @ 2451456
//  part   [16][64][80][256] f32 @ 3762176  (per-block sumx partials, NON-atomic)

typedef __bf16 bf16x8 __attribute__((ext_vector_type(8)));
typedef float  f32x4  __attribute__((ext_vector_type(4)));
typedef unsigned char u8;

__device__ __forceinline__ unsigned short f2b(float f) {
  unsigned u = __float_as_uint(f);
  return (unsigned short)((u + 0x7fffu + ((u >> 16) & 1u)) >> 16);
}
__device__ __forceinline__ float b2f(unsigned short s) {
  return __uint_as_float((unsigned)s << 16);
}

// ---------------- K0a: normalized centroids [c][n] + zero cntg ----------------
__global__ __launch_bounds__(256) void k0_cnorm(const float* __restrict__ cent,
                                                float* __restrict__ cnT,
                                                int* __restrict__ cntg) {
  int n = blockIdx.x, t = threadIdx.x;
  if (t < 16) cntg[n * 16 + t] = 0;
  float v = cent[n * 256 + t];
  float s = v * v;
  #pragma unroll
  for (int o = 32; o > 0; o >>= 1) s += __shfl_down(s, o, 64);
  __shared__ float red[4];
  if ((t & 63) == 0) red[t >> 6] = s;
  __syncthreads();
  float tot = red[0] + red[1] + red[2] + red[3];
  float dn = fmaxf(sqrtf(tot), 1e-12f);
  cnT[t * 80 + n] = v / dn;
}

// ---------------- K0b: W prep: bf16 k-sliced [k][o][32] + W^T f32 -------------
__global__ __launch_bounds__(256) void k0_wprep(const float* __restrict__ fcw,
                                                unsigned short* __restrict__ wks,
                                                float* __restrict__ wt) {
  int o = blockIdx.x, c = threadIdx.x;
  float w = fcw[o * 256 + c];
  wt[c * 256 + o] = w;
  wks[((c >> 5) * 256 + o) * 32 + (c & 31)] = f2b(w);
}

// ---- K1F: argmax (f32, exact) + fsq + counts + one-hot MFMA sumx partial -----
// __launch_bounds__(256, 2): VGPR cap 256. g[80] (argmax) and acc[5][4] (sumx)
// have disjoint live ranges -> both stay in registers, no scratch spill.
__global__ __launch_bounds__(256, 2) void k1f(const float* __restrict__ feat,
                                              const float* __restrict__ cnT,
                                              u8* __restrict__ idxb,
                                              float* __restrict__ fsqg,
                                              int* __restrict__ cntg,
                                              float* __restrict__ part) {
  __shared__ alignas(8) u8 idxl[256];
  __shared__ int lh[80];
  const int b = blockIdx.x >> 6, chunk = blockIdx.x & 63;
  const int px0 = chunk << 8;
  const int t = threadIdx.x, wv = t >> 6, ln = t & 63, lo = ln & 15, hi = ln >> 4;
  if (t < 80) lh[t] = 0;
  __syncthreads();

  // ---- argmax phase: EXACT code/order of the proven k1 (identical idx) ----
  const int pi = px0 | t;
  const float* fb = feat + (size_t)b * 256 * 16384 + pi;
  float g[80];
  #pragma unroll
  for (int n = 0; n < 80; ++n) g[n] = 0.f;
  float fsq = 0.f;
  #pragma unroll 4
  for (int c = 0; c < 256; ++c) {
    float v = fb[(size_t)c * 16384];
    fsq = fmaf(v, v, fsq);
    const float* cr = cnT + c * 80;
    #pragma unroll
    for (int n = 0; n < 80; ++n) g[n] = fmaf(v, cr[n], g[n]);
  }
  float best = g[0]; int bi = 0;
  #pragma unroll
  for (int n = 1; n < 80; ++n) if (g[n] > best) { best = g[n]; bi = n; }
  idxb[b * 16384 + pi] = (u8)bi;
  fsqg[b * 16384 + pi] = fsq;
  idxl[t] = (u8)bi;
  atomicAdd(&lh[bi], 1);
  __syncthreads();
  if (t < 80) atomicAdd(&cntg[b * 80 + t], lh[t]);

  // ---- sumx phase: one-hot MFMA over this block's 256 px (feat L3-hot) ----
  f32x4 acc[5][4];
  f32x4 zz = {0.f, 0.f, 0.f, 0.f};
  #pragma unroll
  for (int mt = 0; mt < 5; ++mt)
    #pragma unroll
    for (int nt = 0; nt < 4; ++nt) acc[mt][nt] = zz;
  const int chb = wv * 64;
  #pragma unroll 2
  for (int ks = 0; ks < 8; ++ks) {
    uint2 iv = *(const uint2*)&idxl[ks * 32 + hi * 8];
    int id[8];
    #pragma unroll
    for (int j = 0; j < 4; ++j) { id[j] = (iv.x >> (8 * j)) & 255; id[4 + j] = (iv.y >> (8 * j)) & 255; }
    bf16x8 bfr[4];
    #pragma unroll
    for (int nt = 0; nt < 4; ++nt) {
      const float* bp = feat + ((size_t)b * 256 + chb + nt * 16 + lo) * 16384 + px0 + ks * 32 + hi * 8;
      float4 v0 = *(const float4*)bp;
      float4 v1 = *(const float4*)(bp + 4);
      union { unsigned short u[8]; bf16x8 v; } bb;
      bb.u[0] = f2b(v0.x); bb.u[1] = f2b(v0.y); bb.u[2] = f2b(v0.z); bb.u[3] = f2b(v0.w);
      bb.u[4] = f2b(v1.x); bb.u[5] = f2b(v1.y); bb.u[6] = f2b(v1.z); bb.u[7] = f2b(v1.w);
      bfr[nt] = bb.v;
    }
    #pragma unroll
    for (int mt = 0; mt < 5; ++mt) {
      int row = mt * 16 + lo;
      union { unsigned short u[8]; bf16x8 v; } ma;
      #pragma unroll
      for (int j = 0; j < 8; ++j) ma.u[j] = (id[j] == row) ? (unsigned short)0x3F80 : (unsigned short)0;
      #pragma unroll
      for (int nt = 0; nt < 4; ++nt)
        acc[mt][nt] = __builtin_amdgcn_mfma_f32_16x16x32_bf16(ma.v, bfr[nt], acc[mt][nt], 0, 0, 0);
    }
  }
  // block-owned partial write: NO atomics, coalesced
  float* pb = part + ((size_t)(b * 64 + chunk) * 80) * 256;
  #pragma unroll
  for (int mt = 0; mt < 5; ++mt)
    #pragma unroll
    for (int nt = 0; nt < 4; ++nt)
      #pragma unroll
      for (int r = 0; r < 4; ++r)
        pb[(mt * 16 + hi * 4 + r) * 256 + chb + nt * 16 + lo] = acc[mt][nt][r];
}

// -------- K2: cent = Σ64 partials / max(cnt,1); csq; centf; chat = W*cent -----
__global__ __launch_bounds__(256) void k2_cent(const float* __restrict__ part,
                                               const int* __restrict__ cntg,
                                               const float* __restrict__ wt,
                                               unsigned short* __restrict__ centf,
                                               float* __restrict__ csqg,
                                               float* __restrict__ chatg) {
  int bn = blockIdx.x; int b = bn / 80, n = bn - b * 80; int t = threadIdx.x;
  float dn = fmaxf((float)cntg[bn], 1.0f);
  float s = 0.f;
  const float* pp = part + ((size_t)(b * 64) * 80 + n) * 256 + t;
  #pragma unroll 8
  for (int ck = 0; ck < 64; ++ck) s += pp[(size_t)ck * 80 * 256];
  float cv = s / dn;
  __shared__ float cl[256];
  __shared__ float red[4];
  cl[t] = cv;
  centf[(size_t)bn * 256 + t] = f2b(cv);
  float q = cv * cv;
  #pragma unroll
  for (int o = 32; o > 0; o >>= 1) q += __shfl_down(q, o, 64);
  if ((t & 63) == 0) red[t >> 6] = q;
  __syncthreads();
  if (t == 0) csqg[bn] = red[0] + red[1] + red[2] + red[3];
  float acc = 0.f;
  #pragma unroll 4
  for (int c = 0; c < 256; ++c) acc = fmaf(wt[c * 256 + t], cl[c], acc);
  chatg[(size_t)bn * 256 + t] = acc;
}

// ---------------- K3b: pipelined W-in-registers MFMA GEMM + alpha + epilogue --
__global__ __launch_bounds__(512) void k3b_gemm(const float* __restrict__ feat,
    const u8* __restrict__ idxb, const float* __restrict__ fsqg,
    const float* __restrict__ csqg, const unsigned short* __restrict__ centf,
    const float* __restrict__ chatg, const unsigned short* __restrict__ wks,
    const float* __restrict__ fcb, float* __restrict__ out) {
  __shared__ alignas(16) unsigned short featT[2][64 * 264];  // double-buffered
  __shared__ float alphal[64];
  __shared__ int cidl[64];
  const int t = threadIdx.x;
  const int w = t >> 6, ln = t & 63, lo = ln & 15, hi = ln >> 4;
  const int pl = ln, cph = w;

  bf16x8 wf[2][8];
  #pragma unroll
  for (int ml = 0; ml < 2; ++ml)
    #pragma unroll
    for (int ks = 0; ks < 8; ++ks)
      wf[ml][ks] = *(const bf16x8*)&wks[((size_t)ks * 256 + (w * 2 + ml) * 16 + lo) * 32 + hi * 8];
  f32x4 bias2[2];
  #pragma unroll
  for (int ml = 0; ml < 2; ++ml)
    bias2[ml] = *(const f32x4*)&fcb[w * 32 + ml * 16 + hi * 4];

  const int tile0 = blockIdx.x * 8;
  {
    int b = tile0 >> 8, p0 = (tile0 & 255) << 6;
    const float* fb = feat + ((size_t)b * 256 + cph * 32) * 16384 + p0 + pl;
    #pragma unroll
    for (int jj = 0; jj < 4; ++jj) {
      union { unsigned short u[8]; uint4 q; } pk;
      #pragma unroll
      for (int e = 0; e < 8; ++e) pk.u[e] = f2b(fb[(size_t)(jj * 8 + e) * 16384]);
      *(uint4*)&featT[0][pl * 264 + cph * 32 + jj * 8] = pk.q;
    }
  }

  float nxv[32];
  for (int rep = 0; rep < 8; ++rep) {
    const int cur = rep & 1;
    const int tile = tile0 + rep;
    const int b = tile >> 8, p0 = (tile & 255) << 6;

    __syncthreads();

    if (rep < 7) {
      int t2 = tile + 1;
      int b2 = t2 >> 8, p02 = (t2 & 255) << 6;
      const float* fb2 = feat + ((size_t)b2 * 256 + cph * 32) * 16384 + p02 + pl;
      #pragma unroll
      for (int e = 0; e < 32; ++e) nxv[e] = fb2[(size_t)e * 16384];
    }

    {
      int p = t >> 3, sub = t & 7;
      int cid = idxb[b * 16384 + p0 + p];
      const unsigned short* cw = centf + ((size_t)b * 80 + cid) * 256 + sub * 32;
      const unsigned short* fr = &featT[cur][p * 264 + sub * 32];
      float sel = 0.f;
      #pragma unroll
      for (int j = 0; j < 4; ++j) {
        uint4 cc = *(const uint4*)&cw[j * 8];
        uint4 ff = *(const uint4*)&fr[j * 8];
        sel = fmaf(b2f((unsigned short)(ff.x & 0xffff)), b2f((unsigned short)(cc.x & 0xffff)), sel);
        sel = fmaf(b2f((unsigned short)(ff.x >> 16)),    b2f((unsigned short)(cc.x >> 16)),    sel);
        sel = fmaf(b2f((unsigned short)(ff.y & 0xffff)), b2f((unsigned short)(cc.y & 0xffff)), sel);
        sel = fmaf(b2f((unsigned short)(ff.y >> 16)),    b2f((unsigned short)(cc.y >> 16)),    sel);
        sel = fmaf(b2f((unsigned short)(ff.z & 0xffff)), b2f((unsigned short)(cc.z & 0xffff)), sel);
        sel = fmaf(b2f((unsigned short)(ff.z >> 16)),    b2f((unsigned short)(cc.z >> 16)),    sel);
        sel = fmaf(b2f((unsigned short)(ff.w & 0xffff)), b2f((unsigned short)(cc.w & 0xffff)), sel);
        sel = fmaf(b2f((unsigned short)(ff.w >> 16)),    b2f((unsigned short)(cc.w >> 16)),    sel);
      }
      sel += __shfl_xor(sel, 1, 64);
      sel += __shfl_xor(sel, 2, 64);
      sel += __shfl_xor(sel, 4, 64);
      if (sub == 0) {
        float fsq = fsqg[b * 16384 + p0 + p];
        float msq = (csqg[b * 80 + cid] - 2.f * sel + fsq) * (1.f / 256.f);
        alphal[p] = expf(-msq);
        cidl[p] = cid;
      }
    }

    f32x4 acc[2][4];
    f32x4 zz = {0.f, 0.f, 0.f, 0.f};
    #pragma unroll
    for (int ml = 0; ml < 2; ++ml)
      #pragma unroll
      for (int pt = 0; pt < 4; ++pt) acc[ml][pt] = zz;

    #pragma unroll
    for (int ks = 0; ks < 8; ++ks) {
      bf16x8 bfr[4];
      #pragma unroll
      for (int pt = 0; pt < 4; ++pt)
        bfr[pt] = *(const bf16x8*)&featT[cur][(pt * 16 + lo) * 264 + ks * 32 + hi * 8];
      #pragma unroll
      for (int ml = 0; ml < 2; ++ml)
        #pragma unroll
        for (int pt = 0; pt < 4; ++pt)
          acc[ml][pt] = __builtin_amdgcn_mfma_f32_16x16x32_bf16(wf[ml][ks], bfr[pt], acc[ml][pt], 0, 0, 0);
    }
    __syncthreads();

    #pragma unroll
    for (int pt = 0; pt < 4; ++pt) {
      int plx = pt * 16 + lo;
      int p = p0 + plx;
      float a = alphal[plx];
      float om = 1.f - a;
      const float* crow = chatg + ((size_t)b * 80 + cidl[plx]) * 256;
      #pragma unroll
      for (int ml = 0; ml < 2; ++ml) {
        int o0 = w * 32 + ml * 16 + hi * 4;
        float4 c4 = *(const float4*)&crow[o0];
        size_t ob = ((size_t)b * 256 + o0) * 16384 + p;
        out[ob            ] = fmaxf(fmaf(a, c4.x, om * acc[ml][pt][0]) + bias2[ml][0], 0.f);
        out[ob + 16384    ] = fmaxf(fmaf(a, c4.y, om * acc[ml][pt][1]) + bias2[ml][1], 0.f);
        out[ob + 2 * 16384] = fmaxf(fmaf(a, c4.z, om * acc[ml][pt][2]) + bias2[ml][2], 0.f);
        out[ob + 3 * 16384] = fmaxf(fmaf(a, c4.w, om * acc[ml][pt][3]) + bias2[ml][3], 0.f);
      }
    }

    if (rep < 7) {
      #pragma unroll
      for (int jj = 0; jj < 4; ++jj) {
        union { unsigned short u[8]; uint4 q; } pk;
        #pragma unroll
        for (int e = 0; e < 8; ++e) pk.u[e] = f2b(nxv[jj * 8 + e]);
        *(uint4*)&featT[cur ^ 1][pl * 264 + cph * 32 + jj * 8] = pk.q;
      }
    }
  }
}

extern "C" void kernel_launch(void* const* d_in, const int* in_sizes, int n_in,
                              void* d_out, int out_size, void* d_ws, size_t ws_size,
                              hipStream_t stream) {
  (void)in_sizes; (void)n_in; (void)out_size; (void)ws_size;
  const float* feat = (const float*)d_in[0];
  const float* cent = (const float*)d_in[1];
  const float* fcw  = (const float*)d_in[2];
  const float* fcb  = (const float*)d_in[3];
  float* out = (float*)d_out;
  char* ws = (char*)d_ws;
  float* cnT             = (float*)(ws);
  float* wt              = (float*)(ws + 81920);
  unsigned short* wks    = (unsigned short*)(ws + 344064);
  unsigned short* centf  = (unsigned short*)(ws + 475136);
  u8*    idxb            = (u8*)(ws + 1130496);
  float* fsq             = (float*)(ws + 1392640);
  int*   cntg            = (int*)(ws + 2441216);
  float* csq             = (float*)(ws + 2446336);
  float* chat            = (float*)(ws + 2451456);
  float* part            = (float*)(ws + 3762176);

  k0_cnorm<<<80, 256, 0, stream>>>(cent, cnT, cntg);
  k0_wprep<<<256, 256, 0, stream>>>(fcw, wks, wt);
  k1f<<<1024, 256, 0, stream>>>(feat, cnT, idxb, fsq, cntg, part);
  k2_cent<<<1280, 256, 0, stream>>>(part, cntg, wt, centf, csq, chat);
  k3b_gemm<<<512, 512, 0, stream>>>(feat, idxb, fsq, csq, centf, chat, wks, fcb, out);
}

// Round 16
// 389.899 us; speedup vs baseline: 1.6985x; 1.1016x over previous
//
#include <hip/hip_runtime.h>

// Refine: out = relu((1-a)*(W f) + a*chat[idx] + bias)
// a = exp(-(csq - 2*<f,cent[idx]> + fsq)/256), chat = W*cent
// idx = argmax_n <f, cnorm_n>
//
// ws layout (1 GiB available; ~88 MB used):
//  cnT    [256][80] f32        @ 0
//  wt     [256][256] f32       @ 81920
//  wks    [8][256][32] bf16    @ 344064
//  centf  [16][80][256] bf16   @ 475136
//  idxb   [16*16384] u8        @ 1130496
//  fsq    [16*16384] f32       @ 1392640
//  cnt    [16*80] i32          @ 2441216  (zeroed by k0_cnorm)
//  csq    [16*80] f32          @ 2446336
//  chat   [16][80][256] f32    @ 2451456
//  part   [16][64][80][256] f32 @ 3762176  (per-block sumx partials, NON-atomic)

typedef __bf16 bf16x8 __attribute__((ext_vector_type(8)));
typedef float  f32x4  __attribute__((ext_vector_type(4)));
typedef unsigned char u8;

__device__ __forceinline__ unsigned short f2b(float f) {
  unsigned u = __float_as_uint(f);
  return (unsigned short)((u + 0x7fffu + ((u >> 16) & 1u)) >> 16);
}
__device__ __forceinline__ float b2f(unsigned short s) {
  return __uint_as_float((unsigned)s << 16);
}

// ---------------- K0a: normalized centroids [c][n] + zero cntg ----------------
__global__ __launch_bounds__(256) void k0_cnorm(const float* __restrict__ cent,
                                                float* __restrict__ cnT,
                                                int* __restrict__ cntg) {
  int n = blockIdx.x, t = threadIdx.x;
  if (t < 16) cntg[n * 16 + t] = 0;
  float v = cent[n * 256 + t];
  float s = v * v;
  #pragma unroll
  for (int o = 32; o > 0; o >>= 1) s += __shfl_down(s, o, 64);
  __shared__ float red[4];
  if ((t & 63) == 0) red[t >> 6] = s;
  __syncthreads();
  float tot = red[0] + red[1] + red[2] + red[3];
  float dn = fmaxf(sqrtf(tot), 1e-12f);
  cnT[t * 80 + n] = v / dn;
}

// ---------------- K0b: W prep: bf16 k-sliced [k][o][32] + W^T f32 -------------
__global__ __launch_bounds__(256) void k0_wprep(const float* __restrict__ fcw,
                                                unsigned short* __restrict__ wks,
                                                float* __restrict__ wt) {
  int o = blockIdx.x, c = threadIdx.x;
  float w = fcw[o * 256 + c];
  wt[c * 256 + o] = w;
  wks[((c >> 5) * 256 + o) * 32 + (c & 31)] = f2b(w);
}

// ---- K1F: argmax (f32, exact, 2 class-halves) + fsq + counts + sumx ----------
// Register budget: argmax peak ~55 VGPR (g[40]); sumx peak ~45 VGPR + 40 AGPR
// (acc[5][2], 2 channel-half passes). Static ~100 unified -> 5 waves/SIMD.
__global__ __launch_bounds__(256, 4) void k1f(const float* __restrict__ feat,
                                              const float* __restrict__ cnT,
                                              u8* __restrict__ idxb,
                                              float* __restrict__ fsqg,
                                              int* __restrict__ cntg,
                                              float* __restrict__ part) {
  __shared__ alignas(8) u8 idxl[256];
  __shared__ int lh[80];
  const int b = blockIdx.x >> 6, chunk = blockIdx.x & 63;
  const int px0 = chunk << 8;
  const int t = threadIdx.x, wv = t >> 6, ln = t & 63, lo = ln & 15, hi = ln >> 4;
  if (t < 80) lh[t] = 0;
  __syncthreads();

  // ---- argmax: classes 0..39 (+fsq), then 40..79; exact merge ----
  const int pi = px0 | t;
  const float* fb = feat + (size_t)b * 256 * 16384 + pi;
  float best, fsq; int bi;
  {
    float g[40];
    #pragma unroll
    for (int n = 0; n < 40; ++n) g[n] = 0.f;
    fsq = 0.f;
    #pragma unroll 4
    for (int c = 0; c < 256; ++c) {
      float v = fb[(size_t)c * 16384];
      fsq = fmaf(v, v, fsq);
      const float* cr = cnT + c * 80;
      #pragma unroll
      for (int n = 0; n < 40; ++n) g[n] = fmaf(v, cr[n], g[n]);
    }
    best = g[0]; bi = 0;
    #pragma unroll
    for (int n = 1; n < 40; ++n) if (g[n] > best) { best = g[n]; bi = n; }
  }
  {
    float g[40];
    #pragma unroll
    for (int n = 0; n < 40; ++n) g[n] = 0.f;
    #pragma unroll 4
    for (int c = 0; c < 256; ++c) {
      float v = fb[(size_t)c * 16384];            // L2/L3-hot re-read
      const float* cr = cnT + c * 80 + 40;
      #pragma unroll
      for (int n = 0; n < 40; ++n) g[n] = fmaf(v, cr[n], g[n]);
    }
    float b2 = g[0]; int i2 = 40;
    #pragma unroll
    for (int n = 1; n < 40; ++n) if (g[n] > b2) { b2 = g[n]; i2 = 40 + n; }
    if (b2 > best) { best = b2; bi = i2; }        // ties keep lower index
  }
  idxb[b * 16384 + pi] = (u8)bi;
  fsqg[b * 16384 + pi] = fsq;
  idxl[t] = (u8)bi;
  atomicAdd(&lh[bi], 1);
  __syncthreads();
  if (t < 80) atomicAdd(&cntg[b * 80 + t], lh[t]);

  // ---- sumx: one-hot MFMA, 2 channel-half passes (acc[5][2] = 40 AGPR) ----
  const int chb = wv * 64;
  float* pb = part + ((size_t)(b * 64 + chunk) * 80) * 256;
  #pragma unroll 1
  for (int half = 0; half < 2; ++half) {
    f32x4 acc[5][2];
    f32x4 zz = {0.f, 0.f, 0.f, 0.f};
    #pragma unroll
    for (int mt = 0; mt < 5; ++mt) { acc[mt][0] = zz; acc[mt][1] = zz; }
    #pragma unroll 2
    for (int ks = 0; ks < 8; ++ks) {
      uint2 iv = *(const uint2*)&idxl[ks * 32 + hi * 8];
      int id[8];
      #pragma unroll
      for (int j = 0; j < 4; ++j) { id[j] = (iv.x >> (8 * j)) & 255; id[4 + j] = (iv.y >> (8 * j)) & 255; }
      bf16x8 bfr[2];
      #pragma unroll
      for (int n2 = 0; n2 < 2; ++n2) {
        int nt = half * 2 + n2;
        const float* bp = feat + ((size_t)b * 256 + chb + nt * 16 + lo) * 16384 + px0 + ks * 32 + hi * 8;
        float4 v0 = *(const float4*)bp;
        float4 v1 = *(const float4*)(bp + 4);
        union { unsigned short u[8]; bf16x8 v; } bb;
        bb.u[0] = f2b(v0.x); bb.u[1] = f2b(v0.y); bb.u[2] = f2b(v0.z); bb.u[3] = f2b(v0.w);
        bb.u[4] = f2b(v1.x); bb.u[5] = f2b(v1.y); bb.u[6] = f2b(v1.z); bb.u[7] = f2b(v1.w);
        bfr[n2] = bb.v;
      }
      #pragma unroll
      for (int mt = 0; mt < 5; ++mt) {
        int row = mt * 16 + lo;
        union { unsigned short u[8]; bf16x8 v; } ma;
        #pragma unroll
        for (int j = 0; j < 8; ++j) ma.u[j] = (id[j] == row) ? (unsigned short)0x3F80 : (unsigned short)0;
        #pragma unroll
        for (int n2 = 0; n2 < 2; ++n2)
          acc[mt][n2] = __builtin_amdgcn_mfma_f32_16x16x32_bf16(ma.v, bfr[n2], acc[mt][n2], 0, 0, 0);
      }
    }
    // block-owned partial write: NO atomics, coalesced
    #pragma unroll
    for (int mt = 0; mt < 5; ++mt)
      #pragma unroll
      for (int n2 = 0; n2 < 2; ++n2)
        #pragma unroll
        for (int r = 0; r < 4; ++r)
          pb[(mt * 16 + hi * 4 + r) * 256 + chb + (half * 2 + n2) * 16 + lo] = acc[mt][n2][r];
  }
}

// -------- K2: cent = Σ64 partials / max(cnt,1); csq; centf; chat = W*cent -----
__global__ __launch_bounds__(256) void k2_cent(const float* __restrict__ part,
                                               const int* __restrict__ cntg,
                                               const float* __restrict__ wt,
                                               unsigned short* __restrict__ centf,
                                               float* __restrict__ csqg,
                                               float* __restrict__ chatg) {
  int bn = blockIdx.x; int b = bn / 80, n = bn - b * 80; int t = threadIdx.x;
  float dn = fmaxf((float)cntg[bn], 1.0f);
  float s = 0.f;
  const float* pp = part + ((size_t)(b * 64) * 80 + n) * 256 + t;
  #pragma unroll 8
  for (int ck = 0; ck < 64; ++ck) s += pp[(size_t)ck * 80 * 256];
  float cv = s / dn;
  __shared__ float cl[256];
  __shared__ float red[4];
  cl[t] = cv;
  centf[(size_t)bn * 256 + t] = f2b(cv);
  float q = cv * cv;
  #pragma unroll
  for (int o = 32; o > 0; o >>= 1) q += __shfl_down(q, o, 64);
  if ((t & 63) == 0) red[t >> 6] = q;
  __syncthreads();
  if (t == 0) csqg[bn] = red[0] + red[1] + red[2] + red[3];
  float acc = 0.f;
  #pragma unroll 4
  for (int c = 0; c < 256; ++c) acc = fmaf(wt[c * 256 + t], cl[c], acc);
  chatg[(size_t)bn * 256 + t] = acc;
}

// ---------------- K3b: pipelined W-in-registers MFMA GEMM + alpha + epilogue --
__global__ __launch_bounds__(512) void k3b_gemm(const float* __restrict__ feat,
    const u8* __restrict__ idxb, const float* __restrict__ fsqg,
    const float* __restrict__ csqg, const unsigned short* __restrict__ centf,
    const float* __restrict__ chatg, const unsigned short* __restrict__ wks,
    const float* __restrict__ fcb, float* __restrict__ out) {
  __shared__ alignas(16) unsigned short featT[2][64 * 264];  // double-buffered
  __shared__ float alphal[64];
  __shared__ int cidl[64];
  const int t = threadIdx.x;
  const int w = t >> 6, ln = t & 63, lo = ln & 15, hi = ln >> 4;
  const int pl = ln, cph = w;

  bf16x8 wf[2][8];
  #pragma unroll
  for (int ml = 0; ml < 2; ++ml)
    #pragma unroll
    for (int ks = 0; ks < 8; ++ks)
      wf[ml][ks] = *(const bf16x8*)&wks[((size_t)ks * 256 + (w * 2 + ml) * 16 + lo) * 32 + hi * 8];
  f32x4 bias2[2];
  #pragma unroll
  for (int ml = 0; ml < 2; ++ml)
    bias2[ml] = *(const f32x4*)&fcb[w * 32 + ml * 16 + hi * 4];

  const int tile0 = blockIdx.x * 8;
  {
    int b = tile0 >> 8, p0 = (tile0 & 255) << 6;
    const float* fb = feat + ((size_t)b * 256 + cph * 32) * 16384 + p0 + pl;
    #pragma unroll
    for (int jj = 0; jj < 4; ++jj) {
      union { unsigned short u[8]; uint4 q; } pk;
      #pragma unroll
      for (int e = 0; e < 8; ++e) pk.u[e] = f2b(fb[(size_t)(jj * 8 + e) * 16384]);
      *(uint4*)&featT[0][pl * 264 + cph * 32 + jj * 8] = pk.q;
    }
  }

  float nxv[32];
  for (int rep = 0; rep < 8; ++rep) {
    const int cur = rep & 1;
    const int tile = tile0 + rep;
    const int b = tile >> 8, p0 = (tile & 255) << 6;

    __syncthreads();

    if (rep < 7) {
      int t2 = tile + 1;
      int b2 = t2 >> 8, p02 = (t2 & 255) << 6;
      const float* fb2 = feat + ((size_t)b2 * 256 + cph * 32) * 16384 + p02 + pl;
      #pragma unroll
      for (int e = 0; e < 32; ++e) nxv[e] = fb2[(size_t)e * 16384];
    }

    {
      int p = t >> 3, sub = t & 7;
      int cid = idxb[b * 16384 + p0 + p];
      const unsigned short* cw = centf + ((size_t)b * 80 + cid) * 256 + sub * 32;
      const unsigned short* fr = &featT[cur][p * 264 + sub * 32];
      float sel = 0.f;
      #pragma unroll
      for (int j = 0; j < 4; ++j) {
        uint4 cc = *(const uint4*)&cw[j * 8];
        uint4 ff = *(const uint4*)&fr[j * 8];
        sel = fmaf(b2f((unsigned short)(ff.x & 0xffff)), b2f((unsigned short)(cc.x & 0xffff)), sel);
        sel = fmaf(b2f((unsigned short)(ff.x >> 16)),    b2f((unsigned short)(cc.x >> 16)),    sel);
        sel = fmaf(b2f((unsigned short)(ff.y & 0xffff)), b2f((unsigned short)(cc.y & 0xffff)), sel);
        sel = fmaf(b2f((unsigned short)(ff.y >> 16)),    b2f((unsigned short)(cc.y >> 16)),    sel);
        sel = fmaf(b2f((unsigned short)(ff.z & 0xffff)), b2f((unsigned short)(cc.z & 0xffff)), sel);
        sel = fmaf(b2f((unsigned short)(ff.z >> 16)),    b2f((unsigned short)(cc.z >> 16)),    sel);
        sel = fmaf(b2f((unsigned short)(ff.w & 0xffff)), b2f((unsigned short)(cc.w & 0xffff)), sel);
        sel = fmaf(b2f((unsigned short)(ff.w >> 16)),    b2f((unsigned short)(cc.w >> 16)),    sel);
      }
      sel += __shfl_xor(sel, 1, 64);
      sel += __shfl_xor(sel, 2, 64);
      sel += __shfl_xor(sel, 4, 64);
      if (sub == 0) {
        float fsq = fsqg[b * 16384 + p0 + p];
        float msq = (csqg[b * 80 + cid] - 2.f * sel + fsq) * (1.f / 256.f);
        alphal[p] = expf(-msq);
        cidl[p] = cid;
      }
    }

    f32x4 acc[2][4];
    f32x4 zz = {0.f, 0.f, 0.f, 0.f};
    #pragma unroll
    for (int ml = 0; ml < 2; ++ml)
      #pragma unroll
      for (int pt = 0; pt < 4; ++pt) acc[ml][pt] = zz;

    #pragma unroll
    for (int ks = 0; ks < 8; ++ks) {
      bf16x8 bfr[4];
      #pragma unroll
      for (int pt = 0; pt < 4; ++pt)
        bfr[pt] = *(const bf16x8*)&featT[cur][(pt * 16 + lo) * 264 + ks * 32 + hi * 8];
      #pragma unroll
      for (int ml = 0; ml < 2; ++ml)
        #pragma unroll
        for (int pt = 0; pt < 4; ++pt)
          acc[ml][pt] = __builtin_amdgcn_mfma_f32_16x16x32_bf16(wf[ml][ks], bfr[pt], acc[ml][pt], 0, 0, 0);
    }
    __syncthreads();

    #pragma unroll
    for (int pt = 0; pt < 4; ++pt) {
      int plx = pt * 16 + lo;
      int p = p0 + plx;
      float a = alphal[plx];
      float om = 1.f - a;
      const float* crow = chatg + ((size_t)b * 80 + cidl[plx]) * 256;
      #pragma unroll
      for (int ml = 0; ml < 2; ++ml) {
        int o0 = w * 32 + ml * 16 + hi * 4;
        float4 c4 = *(const float4*)&crow[o0];
        size_t ob = ((size_t)b * 256 + o0) * 16384 + p;
        out[ob            ] = fmaxf(fmaf(a, c4.x, om * acc[ml][pt][0]) + bias2[ml][0], 0.f);
        out[ob + 16384    ] = fmaxf(fmaf(a, c4.y, om * acc[ml][pt][1]) + bias2[ml][1], 0.f);
        out[ob + 2 * 16384] = fmaxf(fmaf(a, c4.z, om * acc[ml][pt][2]) + bias2[ml][2], 0.f);
        out[ob + 3 * 16384] = fmaxf(fmaf(a, c4.w, om * acc[ml][pt][3]) + bias2[ml][3], 0.f);
      }
    }

    if (rep < 7) {
      #pragma unroll
      for (int jj = 0; jj < 4; ++jj) {
        union { unsigned short u[8]; uint4 q; } pk;
        #pragma unroll
        for (int e = 0; e < 8; ++e) pk.u[e] = f2b(nxv[jj * 8 + e]);
        *(uint4*)&featT[cur ^ 1][pl * 264 + cph * 32 + jj * 8] = pk.q;
      }
    }
  }
}

extern "C" void kernel_launch(void* const* d_in, const int* in_sizes, int n_in,
                              void* d_out, int out_size, void* d_ws, size_t ws_size,
                              hipStream_t stream) {
  (void)in_sizes; (void)n_in; (void)out_size; (void)ws_size;
  const float* feat = (const float*)d_in[0];
  const float* cent = (const float*)d_in[1];
  const float* fcw  = (const float*)d_in[2];
  const float* fcb  = (const float*)d_in[3];
  float* out = (float*)d_out;
  char* ws = (char*)d_ws;
  float* cnT             = (float*)(ws);
  float* wt              = (float*)(ws + 81920);
  unsigned short* wks    = (unsigned short*)(ws + 344064);
  unsigned short* centf  = (unsigned short*)(ws + 475136);
  u8*    idxb            = (u8*)(ws + 1130496);
  float* fsq             = (float*)(ws + 1392640);
  int*   cntg            = (int*)(ws + 2441216);
  float* csq             = (float*)(ws + 2446336);
  float* chat            = (float*)(ws + 2451456);
  float* part            = (float*)(ws + 3762176);

  k0_cnorm<<<80, 256, 0, stream>>>(cent, cnT, cntg);
  k0_wprep<<<256, 256, 0, stream>>>(fcw, wks, wt);
  k1f<<<1024, 256, 0, stream>>>(feat, cnT, idxb, fsq, cntg, part);
  k2_cent<<<1280, 256, 0, stream>>>(part, cntg, wt, centf, csq, chat);
  k3b_gemm<<<512, 512, 0, stream>>>(feat, idxb, fsq, csq, centf, chat, wks, fcb, out);
}